// Round 2
// baseline (596.382 us; speedup 1.0000x reference)
//
#include <hip/hip_runtime.h>
#include <hip/hip_bf16.h>
#include <cstdint>

// ---------------------------------------------------------------------------
// MultiHeadAttention (B=4, L=2048, d_model=1024, 16 heads, d_k=d_v=64)
// Inputs/outputs fp32. Internals: bf16 MFMA, fp32 accum.
// R2: V pre-transposed by QKV-GEMM epilogue; attn LDS stride 72.
// R3: no-max softmax (exp2, Q pre-scaled by log2e/32), deferred row-sum,
//     key-permuted P, 32 q-rows per wave.
// R4: pi-permutation moved into global Vt (GEMM epilogue stores pi-ordered,
//     attention bv = direct b128 reads); GEMMs use global_load_lds width-16.
// R5: attn T14 async-STAGE split + T5 setprio around MFMA clusters.
// R6: attn K-fragments read DIRECT from global (L1/L2-resident; Ks LDS array
//     and its staging deleted -> LDS pipe was saturated at ~28KB/wave-tile);
//     repack_w rewritten as coalesced LDS-transpose.
// ---------------------------------------------------------------------------

typedef __attribute__((ext_vector_type(8))) short   short8;
typedef __attribute__((ext_vector_type(8))) __bf16  bf16x8;
typedef __attribute__((ext_vector_type(4))) float   float4v;

template <typename V>
__device__ __forceinline__ auto mfma_sel(V a, V b, float4v c, int)
    -> decltype(__builtin_amdgcn_mfma_f32_16x16x32_bf16(a, b, c, 0, 0, 0)) {
  return __builtin_amdgcn_mfma_f32_16x16x32_bf16(a, b, c, 0, 0, 0);
}
template <typename V>
__device__ __forceinline__ float4v mfma_sel(V a, V b, float4v c, long) {
  return __builtin_amdgcn_mfma_f32_16x16x32_bf16(
      __builtin_bit_cast(bf16x8, a), __builtin_bit_cast(bf16x8, b), c, 0, 0, 0);
}
__device__ __forceinline__ float4v MFMA(short8 a, short8 b, float4v c) {
  return mfma_sel(a, b, c, 0);
}

__device__ __forceinline__ unsigned short f2b(float f) {
  union { float f; unsigned int u; } x; x.f = f;
  unsigned int r = x.u + 0x7FFFu + ((x.u >> 16) & 1u);  // RNE
  return (unsigned short)(r >> 16);
}
__device__ __forceinline__ unsigned int fu(float f) {
  union { float f; unsigned int u; } x; x.f = f; return x.u;
}
__device__ __forceinline__ float fast_exp2(float x) {
#if __has_builtin(__builtin_amdgcn_exp2f)
  return __builtin_amdgcn_exp2f(x);
#else
  return exp2f(x);
#endif
}

// async global->LDS, 16B per lane; LDS dest = wave-uniform base + lane*16
__device__ __forceinline__ void async_cp16(const unsigned short* g, unsigned short* l) {
  __builtin_amdgcn_global_load_lds(
      (const __attribute__((address_space(1))) void*)g,
      (__attribute__((address_space(3))) void*)l, 16, 0, 0);
}

constexpr int Bb = 4, Ls = 2048, Dm = 1024, NH = 16;
constexpr int Mrows = Bb * Ls;          // 8192
constexpr int NQKV = 3 * Dm;            // 3072
constexpr int NQ_ELEMS = Mrows * Dm;    // 8388608
constexpr int NP_ELEMS = Dm * Dm;       // 1048576
constexpr int PAD = 72;                 // LDS row stride (halfwords), 144B

// --- fp32 -> bf16 conversion for q (8M) and proj_w (1M)
__global__ __launch_bounds__(256) void conv_kernel(const float* __restrict__ q,
                                                   const float* __restrict__ pw,
                                                   unsigned short* __restrict__ Qb,
                                                   unsigned short* __restrict__ Pb) {
  int idx = blockIdx.x * 256 + threadIdx.x;  // 9437184 total
  if (idx < NQ_ELEMS) Qb[idx] = f2b(q[idx]);
  else                Pb[idx - NQ_ELEMS] = f2b(pw[idx - NQ_ELEMS]);
}

// --- repack fp32 w_qs/w_ks/w_vs [16][1024][64] -> bf16 Wt[3072][1024]
// R6: LDS-transpose version. Block = (which, h, d-tile of 64); reads are
// lane-contiguous over kk (256B/row), writes vectorized 32B/thread.
__global__ __launch_bounds__(256) void repack_w(const float* __restrict__ wq,
                                                const float* __restrict__ wk,
                                                const float* __restrict__ wv,
                                                unsigned short* __restrict__ Wt) {
  const int bid = blockIdx.x;          // 768 blocks
  const int which = bid >> 8;          // 0,1,2
  const int h = (bid >> 4) & 15, dt = bid & 15;
  const float* w = (which == 0) ? wq : (which == 1 ? wk : wv);

  __shared__ float tile[64][65];
  const int kk = threadIdx.x & 63, dd = threadIdx.x >> 6;  // 4 rows/pass
#pragma unroll
  for (int p = 0; p < 16; ++p) {
    int d = dt * 64 + p * 4 + dd;
    tile[p * 4 + dd][kk] = w[(size_t)(h * 1024 + d) * 64 + kk];
  }
  __syncthreads();
  const int kkw = threadIdx.x >> 2, c0 = (threadIdx.x & 3) * 16;
  unsigned short tmp[16];
#pragma unroll
  for (int j = 0; j < 16; ++j) tmp[j] = f2b(tile[c0 + j][kkw]);
  unsigned short* dst =
      Wt + (size_t)(which * 1024 + h * 64 + kkw) * 1024 + dt * 64 + c0;
  *(uint4*)&dst[0] = *(const uint4*)&tmp[0];
  *(uint4*)&dst[8] = *(const uint4*)&tmp[8];
}

// --- C = A[M][K] * Bt[N][K]^T (bf16), 128x128 tile, BK=32, 4 waves 64x64,
// async global_load_lds width-16 staging.
// MODE 0 (QKV): cols<1024 -> Q scaled by log2e/32 -> QK; [1024,2048) -> K
//   -> QK. cols>=2048 -> V stored pi-ordered into Vt[dv][8192]:
//   Vt[dv][64*(t/64) + pi(t%64)], pi(16*jn+r) = 4*r+jn. Each lane holds the
//   16 values for 16 contiguous pi-positions [16q,16q+16): p=16q+4*rg+i.
// MODE 1 (proj): +bias(f32) +residual(f32), store fp32 Cf[row*N+col].
template <int MODE>
__global__ __launch_bounds__(256) void gemm_bt(const unsigned short* __restrict__ A,
                                               const unsigned short* __restrict__ Bt,
                                               unsigned short* __restrict__ QK,
                                               unsigned short* __restrict__ Vt,
                                               float* __restrict__ Cf,
                                               const float* __restrict__ bias,
                                               const float* __restrict__ resid,
                                               int N, int K) {
  __shared__ __align__(16) unsigned short As[128 * 32];
  __shared__ __align__(16) unsigned short Bs[128 * 32];
  const int tid = threadIdx.x;
  const int lane = tid & 63, w = tid >> 6;
  const int wm = (w >> 1) * 64, wn = (w & 1) * 64;
  const int m0 = blockIdx.y * 128, n0 = blockIdx.x * 128;
  const int r = lane & 15, q = lane >> 4;

  // staging maps: issue covers 64 rows; wave w covers rows 16w..16w+16
  const unsigned short* gA = A + (size_t)(m0 + 16 * w + (lane >> 2)) * K + (lane & 3) * 8;
  const unsigned short* gB = Bt + (size_t)(n0 + 16 * w + (lane >> 2)) * K + (lane & 3) * 8;
  unsigned short* lA0 = As + 16 * w * 32;
  unsigned short* lA1 = As + (64 + 16 * w) * 32;
  unsigned short* lB0 = Bs + 16 * w * 32;
  unsigned short* lB1 = Bs + (64 + 16 * w) * 32;

  float4v acc[4][4] = {};

  for (int k0 = 0; k0 < K; k0 += 32) {
    async_cp16(gA + k0, lA0);
    async_cp16(gA + (size_t)64 * K + k0, lA1);
    async_cp16(gB + k0, lB0);
    async_cp16(gB + (size_t)64 * K + k0, lB1);
    __syncthreads();
    short8 af[4], bfr[4];
#pragma unroll
    for (int i = 0; i < 4; ++i)
      af[i] = *(const short8*)&As[(wm + i * 16 + r) * 32 + q * 8];
#pragma unroll
    for (int j = 0; j < 4; ++j)
      bfr[j] = *(const short8*)&Bs[(wn + j * 16 + r) * 32 + q * 8];
#pragma unroll
    for (int i = 0; i < 4; ++i)
#pragma unroll
      for (int j = 0; j < 4; ++j)
        acc[i][j] = MFMA(af[i], bfr[j], acc[i][j]);
    __syncthreads();
  }

  if (MODE == 0 && n0 >= 2048) {
    // pi-ordered V: lane writes positions [16q, 16q+16) of token-tile m0+wm
#pragma unroll
    for (int j = 0; j < 4; ++j) {
      int dv = n0 + wn + j * 16 + r - 2048;
      unsigned short t16[16];
#pragma unroll
      for (int i = 0; i < 4; ++i)
#pragma unroll
        for (int rg = 0; rg < 4; ++rg)
          t16[4 * rg + i] = f2b(acc[i][j][rg]);
      unsigned short* dst = Vt + (size_t)dv * 8192 + (m0 + wm) + 16 * q;
      *(uint4*)&dst[0] = *(const uint4*)&t16[0];
      *(uint4*)&dst[8] = *(const uint4*)&t16[8];
    }
  } else {
    const float qscale = (MODE == 0 && n0 < 1024) ? 0.045084230f /*log2e/32*/ : 1.0f;
#pragma unroll
    for (int i = 0; i < 4; ++i)
#pragma unroll
      for (int j = 0; j < 4; ++j)
#pragma unroll
        for (int rg = 0; rg < 4; ++rg) {
          int row = m0 + wm + i * 16 + q * 4 + rg;
          int col = n0 + wn + j * 16 + r;
          float v = acc[i][j][rg];
          if (MODE == 0) {
            QK[(size_t)row * 2048 + col] = f2b(v * qscale);
          } else {
            v += bias[col] + resid[(size_t)row * N + col];
            Cf[(size_t)row * N + col] = v;
          }
        }
  }
}

// --- flash attention (no-max softmax): one block = (h, b, 128 q-rows),
// 4 waves x 32 rows. QK[8192][2048]: cols [0,1024)=Q (pre-scaled by
// log2e/32), [1024,2048)=K. Vt[1024][8192] pi-ordered per 64-token tile.
// R6: K-fragments are read directly from global (K slice is L2/L1-resident;
// all 4 waves share the same lines) with a 1-tile register double-buffer.
// Only V is staged in LDS (pi order enables b128 PV reads); Ps holds P.
__global__ __launch_bounds__(256, 4) void attn_kernel(const unsigned short* __restrict__ QK,
                                                      const unsigned short* __restrict__ Vt,
                                                      unsigned short* __restrict__ O) {
  const int bx = blockIdx.x;
  const int qt = bx & 15, hb = bx >> 4;
  const int h = hb & 15, b = hb >> 4;
  const int tid = threadIdx.x, lane = tid & 63, w = tid >> 6;
  const int r = lane & 15, q = lane >> 4;

  __shared__ __align__(16) unsigned short Vst[64 * PAD];   // [dv][pi(key)]
  __shared__ __align__(16) unsigned short Ps[128 * PAD];   // [qrow][pi(key)]

  const size_t RS = 2048;
  const int l0 = qt * 128;

  short8 aq[2][2];
#pragma unroll
  for (int i = 0; i < 2; ++i) {
    const unsigned short* Qr =
        QK + (size_t)(b * 2048 + l0 + w * 32 + i * 16 + r) * RS + h * 64;
    aq[i][0] = *(const short8*)&Qr[q * 8];
    aq[i][1] = *(const short8*)&Qr[32 + q * 8];
  }

  // V staging maps: c = tid + rep*256, row = c>>3, off = (c&7)*8
  const int row0 = tid >> 3, off0 = (tid & 7) * 8;
  const int row1 = row0 + 32;
  const unsigned short* gV0 = Vt + (size_t)(h * 64 + row0) * 8192 + b * 2048 + off0;
  const unsigned short* gV1 = Vt + (size_t)(h * 64 + row1) * 8192 + b * 2048 + off0;
  unsigned short* lV0 = &Vst[row0 * PAD + off0];
  unsigned short* lV1 = &Vst[row1 * PAD + off0];

  // K direct-load base: lane (r,q), fragment (jn, half x):
  //   QK[(b*2048 + kt + jn*16 + r)*RS + 1024 + h*64 + x*32 + q*8]
  const unsigned short* gK = QK + (size_t)(b * 2048 + r) * RS + 1024 + h * 64 + q * 8;

  // prologue: stage V tile kt=0, load K frags kt=0
  uint4 vr0 = *(const uint4*)gV0;
  uint4 vr1 = *(const uint4*)gV1;
  short8 bk[4][2];
#pragma unroll
  for (int jn = 0; jn < 4; ++jn) {
    bk[jn][0] = *(const short8*)(gK + (size_t)(jn * 16) * RS);
    bk[jn][1] = *(const short8*)(gK + (size_t)(jn * 16) * RS + 32);
  }
  *(uint4*)lV0 = vr0;
  *(uint4*)lV1 = vr1;
  __syncthreads();

  float4v oacc[2][4] = {};
  float lsum[8] = {};

  for (int kt = 0; kt < 2048; kt += 64) {
    const bool has_next = (kt + 64) < 2048;
    // T14: issue next tile's global loads now; they land during compute
    short8 bkn[4][2];
    if (has_next) {
      vr0 = *(const uint4*)(gV0 + (kt + 64));
      vr1 = *(const uint4*)(gV1 + (kt + 64));
#pragma unroll
      for (int jn = 0; jn < 4; ++jn) {
        bkn[jn][0] = *(const short8*)(gK + (size_t)(kt + 64 + jn * 16) * RS);
        bkn[jn][1] = *(const short8*)(gK + (size_t)(kt + 64 + jn * 16) * RS + 32);
      }
    }

    // S = Q K^T (pre-scaled); exp2; accumulate lsum; pack P to LDS (pi order)
#pragma unroll
    for (int i = 0; i < 2; ++i) {
      float4v sacc[4];
      __builtin_amdgcn_s_setprio(1);
#pragma unroll
      for (int jn = 0; jn < 4; ++jn) {
        float4v z = {0.f, 0.f, 0.f, 0.f};
        z = MFMA(aq[i][0], bk[jn][0], z);
        z = MFMA(aq[i][1], bk[jn][1], z);
        sacc[jn] = z;
      }
      __builtin_amdgcn_s_setprio(0);
#pragma unroll
      for (int rg = 0; rg < 4; ++rg) {
        float p0 = fast_exp2(sacc[0][rg]);
        float p1 = fast_exp2(sacc[1][rg]);
        float p2 = fast_exp2(sacc[2][rg]);
        float p3 = fast_exp2(sacc[3][rg]);
        lsum[i * 4 + rg] += (p0 + p1) + (p2 + p3);
        // truncating bf16 pack: halfwords [pi=4r+0..3] = (p0,p1,p2,p3)
        uint2 pk;
        pk.x = __builtin_amdgcn_perm(fu(p1), fu(p0), 0x07060302u);
        pk.y = __builtin_amdgcn_perm(fu(p3), fu(p2), 0x07060302u);
        *(uint2*)&Ps[(w * 32 + i * 16 + q * 4 + rg) * PAD + r * 4] = pk;
      }
    }

    // V fragments: direct b128 reads (Vst already pi-ordered)
    short8 bv[4][2];
#pragma unroll
    for (int jv = 0; jv < 4; ++jv) {
      bv[jv][0] = *(const short8*)&Vst[(jv * 16 + r) * PAD + q * 8];
      bv[jv][1] = *(const short8*)&Vst[(jv * 16 + r) * PAD + 32 + q * 8];
    }

    // O += P V  (P A-frags are direct b128 reads in pi order)
#pragma unroll
    for (int i = 0; i < 2; ++i) {
      short8 ap0 = *(const short8*)&Ps[(w * 32 + i * 16 + r) * PAD + q * 8];
      short8 ap1 = *(const short8*)&Ps[(w * 32 + i * 16 + r) * PAD + 32 + q * 8];
      __builtin_amdgcn_s_setprio(1);
#pragma unroll
      for (int jv = 0; jv < 4; ++jv) {
        oacc[i][jv] = MFMA(ap0, bv[jv][0], oacc[i][jv]);
        oacc[i][jv] = MFMA(ap1, bv[jv][1], oacc[i][jv]);
      }
      __builtin_amdgcn_s_setprio(0);
    }

    // write next V tile into LDS after all waves finished reading current
    if (has_next) {
      __syncthreads();
      *(uint4*)lV0 = vr0;
      *(uint4*)lV1 = vr1;
      __syncthreads();
      // rotate K double-buffer (pure register renames)
#pragma unroll
      for (int jn = 0; jn < 4; ++jn) {
        bk[jn][0] = bkn[jn][0];
        bk[jn][1] = bkn[jn][1];
      }
    }
  }

  // one-time row-sum reduction across the 16 r-lanes
#pragma unroll
  for (int t = 0; t < 8; ++t)
#pragma unroll
    for (int d = 1; d < 16; d <<= 1) lsum[t] += __shfl_xor(lsum[t], d);

#pragma unroll
  for (int i = 0; i < 2; ++i)
#pragma unroll
    for (int jv = 0; jv < 4; ++jv)
#pragma unroll
      for (int rg = 0; rg < 4; ++rg) {
        int row = b * 2048 + l0 + w * 32 + i * 16 + q * 4 + rg;
        int col = h * 64 + jv * 16 + r;
        O[(size_t)row * 1024 + col] = f2b(oacc[i][jv][rg] / lsum[i * 4 + rg]);
      }
}

// --- row LayerNorm: mean, std(ddof=1), /(sigma+1e-3)*a + b  (all fp32)
__global__ __launch_bounds__(256) void ln_kernel(const float* __restrict__ Z,
                                                 const float* __restrict__ ga,
                                                 const float* __restrict__ be,
                                                 float* __restrict__ out) {
  const int row = blockIdx.x;
  const float* z = Z + (size_t)row * 1024;
  const int tid = threadIdx.x;
  float v[4], s = 0.f, sq = 0.f;
#pragma unroll
  for (int i = 0; i < 4; ++i) {
    v[i] = z[tid + i * 256];
    s += v[i];
    sq += v[i] * v[i];
  }
#pragma unroll
  for (int d = 1; d < 64; d <<= 1) { s += __shfl_xor(s, d); sq += __shfl_xor(sq, d); }
  __shared__ float ss[4], ssq[4];
  const int w = tid >> 6, lane = tid & 63;
  if (lane == 0) { ss[w] = s; ssq[w] = sq; }
  __syncthreads();
  s = ss[0] + ss[1] + ss[2] + ss[3];
  sq = ssq[0] + ssq[1] + ssq[2] + ssq[3];
  float mu = s * (1.f / 1024.f);
  float var = fmaxf((sq - 1024.f * mu * mu) * (1.f / 1023.f), 0.f);
  float inv = 1.f / (sqrtf(var) + 1e-3f);
#pragma unroll
  for (int i = 0; i < 4; ++i) {
    int c = tid + i * 256;
    out[(size_t)row * 1024 + c] = (v[i] - mu) * inv * ga[c] + be[c];
  }
}

extern "C" void kernel_launch(void* const* d_in, const int* in_sizes, int n_in,
                              void* d_out, int out_size, void* d_ws, size_t ws_size,
                              hipStream_t stream) {
  (void)in_sizes; (void)n_in; (void)out_size; (void)ws_size;
  const float* q      = (const float*)d_in[0];
  const float* w_qs   = (const float*)d_in[1];
  const float* w_ks   = (const float*)d_in[2];
  const float* w_vs   = (const float*)d_in[3];
  const float* proj_w = (const float*)d_in[4];
  const float* proj_b = (const float*)d_in[5];
  const float* ln_a   = (const float*)d_in[6];
  const float* ln_b   = (const float*)d_in[7];
  float* out = (float*)d_out;

  // ws (88 MB): [Qb 16MB][O 16MB][QK 32MB][Wt 6MB][Pb 2MB][Vt 16MB]
  // Z (fp32, 32MB) aliases QK (dead after attention).
  unsigned short* Qb  = (unsigned short*)d_ws;
  unsigned short* O   = Qb + (size_t)Mrows * Dm;
  unsigned short* QK  = O + (size_t)Mrows * Dm;
  unsigned short* Wt  = QK + (size_t)Mrows * 2048;
  unsigned short* Pb  = Wt + (size_t)NQKV * Dm;
  unsigned short* Vt  = Pb + (size_t)NP_ELEMS;
  float* Z = (float*)QK;

  conv_kernel<<<dim3((NQ_ELEMS + NP_ELEMS) / 256), dim3(256), 0, stream>>>(q, proj_w, Qb, Pb);
  repack_w<<<dim3(768), dim3(256), 0, stream>>>(w_qs, w_ks, w_vs, Wt);
  gemm_bt<0><<<dim3(NQKV / 128, Mrows / 128), dim3(256), 0, stream>>>(
      Qb, Wt, QK, Vt, nullptr, nullptr, nullptr, NQKV, Dm);
  attn_kernel<<<dim3(16 * NH * Bb), dim3(256), 0, stream>>>(QK, Vt, O);
  gemm_bt<1><<<dim3(Dm / 128, Mrows / 128), dim3(256), 0, stream>>>(
      O, Pb, nullptr, nullptr, Z, proj_b, q, Dm, Dm);
  ln_kernel<<<dim3(Mrows), dim3(256), 0, stream>>>(Z, ln_a, ln_b, out);
}

// Round 4
// 377.192 us; speedup vs baseline: 1.5811x; 1.5811x over previous
//
#include <hip/hip_runtime.h>
#include <hip/hip_bf16.h>
#include <cstdint>

// ---------------------------------------------------------------------------
// MultiHeadAttention (B=4, L=2048, d_model=1024, 16 heads, d_k=d_v=64)
// Inputs/outputs fp32. Internals: bf16 MFMA, fp32 accum.
// R2: V pre-transposed by QKV-GEMM epilogue; attn LDS stride 72.
// R3: no-max softmax (exp2, Q pre-scaled by log2e/32), deferred row-sum,
//     key-permuted P, 32 q-rows per wave.
// R4: pi-permutation moved into global Vt; GEMMs use global_load_lds w=16.
// R5: attn T14 async-STAGE split + T5 setprio around MFMA clusters.
// R6 (FAILED): K-direct + __launch_bounds__(256,4) -> hipcc capped VGPR at 64
//     -> bkn prefetch spilled to scratch (WRITE_SIZE 1 GB). Idea untested.
// R7: same K-direct-from-global (Ks LDS deleted, reg double-buffer) but with
//     plain __launch_bounds__(256) so VGPR ~116 < 128, no spill.
// R8: resubmit of R7 (round 3 bench failed on container acquisition —
//     infrastructure, not kernel).
// ---------------------------------------------------------------------------

typedef __attribute__((ext_vector_type(8))) short   short8;
typedef __attribute__((ext_vector_type(8))) __bf16  bf16x8;
typedef __attribute__((ext_vector_type(4))) float   float4v;

template <typename V>
__device__ __forceinline__ auto mfma_sel(V a, V b, float4v c, int)
    -> decltype(__builtin_amdgcn_mfma_f32_16x16x32_bf16(a, b, c, 0, 0, 0)) {
  return __builtin_amdgcn_mfma_f32_16x16x32_bf16(a, b, c, 0, 0, 0);
}
template <typename V>
__device__ __forceinline__ float4v mfma_sel(V a, V b, float4v c, long) {
  return __builtin_amdgcn_mfma_f32_16x16x32_bf16(
      __builtin_bit_cast(bf16x8, a), __builtin_bit_cast(bf16x8, b), c, 0, 0, 0);
}
__device__ __forceinline__ float4v MFMA(short8 a, short8 b, float4v c) {
  return mfma_sel(a, b, c, 0);
}

__device__ __forceinline__ unsigned short f2b(float f) {
  union { float f; unsigned int u; } x; x.f = f;
  unsigned int r = x.u + 0x7FFFu + ((x.u >> 16) & 1u);  // RNE
  return (unsigned short)(r >> 16);
}
__device__ __forceinline__ unsigned int fu(float f) {
  union { float f; unsigned int u; } x; x.f = f; return x.u;
}
__device__ __forceinline__ float fast_exp2(float x) {
#if __has_builtin(__builtin_amdgcn_exp2f)
  return __builtin_amdgcn_exp2f(x);
#else
  return exp2f(x);
#endif
}

// async global->LDS, 16B per lane; LDS dest = wave-uniform base + lane*16
__device__ __forceinline__ void async_cp16(const unsigned short* g, unsigned short* l) {
  __builtin_amdgcn_global_load_lds(
      (const __attribute__((address_space(1))) void*)g,
      (__attribute__((address_space(3))) void*)l, 16, 0, 0);
}

constexpr int Bb = 4, Ls = 2048, Dm = 1024, NH = 16;
constexpr int Mrows = Bb * Ls;          // 8192
constexpr int NQKV = 3 * Dm;            // 3072
constexpr int NQ_ELEMS = Mrows * Dm;    // 8388608
constexpr int NP_ELEMS = Dm * Dm;       // 1048576
constexpr int PAD = 72;                 // LDS row stride (halfwords), 144B

// --- fp32 -> bf16 conversion for q (8M) and proj_w (1M)
__global__ __launch_bounds__(256) void conv_kernel(const float* __restrict__ q,
                                                   const float* __restrict__ pw,
                                                   unsigned short* __restrict__ Qb,
                                                   unsigned short* __restrict__ Pb) {
  int idx = blockIdx.x * 256 + threadIdx.x;  // 9437184 total
  if (idx < NQ_ELEMS) Qb[idx] = f2b(q[idx]);
  else                Pb[idx - NQ_ELEMS] = f2b(pw[idx - NQ_ELEMS]);
}

// --- repack fp32 w_qs/w_ks/w_vs [16][1024][64] -> bf16 Wt[3072][1024]
// R6: LDS-transpose version. Block = (which, h, d-tile of 64); reads are
// lane-contiguous over kk (256B/row), writes vectorized 32B/thread.
__global__ __launch_bounds__(256) void repack_w(const float* __restrict__ wq,
                                                const float* __restrict__ wk,
                                                const float* __restrict__ wv,
                                                unsigned short* __restrict__ Wt) {
  const int bid = blockIdx.x;          // 768 blocks
  const int which = bid >> 8;          // 0,1,2
  const int h = (bid >> 4) & 15, dt = bid & 15;
  const float* w = (which == 0) ? wq : (which == 1 ? wk : wv);

  __shared__ float tile[64][65];
  const int kk = threadIdx.x & 63, dd = threadIdx.x >> 6;  // 4 rows/pass
#pragma unroll
  for (int p = 0; p < 16; ++p) {
    int d = dt * 64 + p * 4 + dd;
    tile[p * 4 + dd][kk] = w[(size_t)(h * 1024 + d) * 64 + kk];
  }
  __syncthreads();
  const int kkw = threadIdx.x >> 2, c0 = (threadIdx.x & 3) * 16;
  unsigned short tmp[16];
#pragma unroll
  for (int j = 0; j < 16; ++j) tmp[j] = f2b(tile[c0 + j][kkw]);
  unsigned short* dst =
      Wt + (size_t)(which * 1024 + h * 64 + kkw) * 1024 + dt * 64 + c0;
  *(uint4*)&dst[0] = *(const uint4*)&tmp[0];
  *(uint4*)&dst[8] = *(const uint4*)&tmp[8];
}

// --- C = A[M][K] * Bt[N][K]^T (bf16), 128x128 tile, BK=32, 4 waves 64x64,
// async global_load_lds width-16 staging.
// MODE 0 (QKV): cols<1024 -> Q scaled by log2e/32 -> QK; [1024,2048) -> K
//   -> QK. cols>=2048 -> V stored pi-ordered into Vt[dv][8192]:
//   Vt[dv][64*(t/64) + pi(t%64)], pi(16*jn+r) = 4*r+jn. Each lane holds the
//   16 values for 16 contiguous pi-positions [16q,16q+16): p=16q+4*rg+i.
// MODE 1 (proj): +bias(f32) +residual(f32), store fp32 Cf[row*N+col].
template <int MODE>
__global__ __launch_bounds__(256) void gemm_bt(const unsigned short* __restrict__ A,
                                               const unsigned short* __restrict__ Bt,
                                               unsigned short* __restrict__ QK,
                                               unsigned short* __restrict__ Vt,
                                               float* __restrict__ Cf,
                                               const float* __restrict__ bias,
                                               const float* __restrict__ resid,
                                               int N, int K) {
  __shared__ __align__(16) unsigned short As[128 * 32];
  __shared__ __align__(16) unsigned short Bs[128 * 32];
  const int tid = threadIdx.x;
  const int lane = tid & 63, w = tid >> 6;
  const int wm = (w >> 1) * 64, wn = (w & 1) * 64;
  const int m0 = blockIdx.y * 128, n0 = blockIdx.x * 128;
  const int r = lane & 15, q = lane >> 4;

  // staging maps: issue covers 64 rows; wave w covers rows 16w..16w+16
  const unsigned short* gA = A + (size_t)(m0 + 16 * w + (lane >> 2)) * K + (lane & 3) * 8;
  const unsigned short* gB = Bt + (size_t)(n0 + 16 * w + (lane >> 2)) * K + (lane & 3) * 8;
  unsigned short* lA0 = As + 16 * w * 32;
  unsigned short* lA1 = As + (64 + 16 * w) * 32;
  unsigned short* lB0 = Bs + 16 * w * 32;
  unsigned short* lB1 = Bs + (64 + 16 * w) * 32;

  float4v acc[4][4] = {};

  for (int k0 = 0; k0 < K; k0 += 32) {
    async_cp16(gA + k0, lA0);
    async_cp16(gA + (size_t)64 * K + k0, lA1);
    async_cp16(gB + k0, lB0);
    async_cp16(gB + (size_t)64 * K + k0, lB1);
    __syncthreads();
    short8 af[4], bfr[4];
#pragma unroll
    for (int i = 0; i < 4; ++i)
      af[i] = *(const short8*)&As[(wm + i * 16 + r) * 32 + q * 8];
#pragma unroll
    for (int j = 0; j < 4; ++j)
      bfr[j] = *(const short8*)&Bs[(wn + j * 16 + r) * 32 + q * 8];
#pragma unroll
    for (int i = 0; i < 4; ++i)
#pragma unroll
      for (int j = 0; j < 4; ++j)
        acc[i][j] = MFMA(af[i], bfr[j], acc[i][j]);
    __syncthreads();
  }

  if (MODE == 0 && n0 >= 2048) {
    // pi-ordered V: lane writes positions [16q, 16q+16) of token-tile m0+wm
#pragma unroll
    for (int j = 0; j < 4; ++j) {
      int dv = n0 + wn + j * 16 + r - 2048;
      unsigned short t16[16];
#pragma unroll
      for (int i = 0; i < 4; ++i)
#pragma unroll
        for (int rg = 0; rg < 4; ++rg)
          t16[4 * rg + i] = f2b(acc[i][j][rg]);
      unsigned short* dst = Vt + (size_t)dv * 8192 + (m0 + wm) + 16 * q;
      *(uint4*)&dst[0] = *(const uint4*)&t16[0];
      *(uint4*)&dst[8] = *(const uint4*)&t16[8];
    }
  } else {
    const float qscale = (MODE == 0 && n0 < 1024) ? 0.045084230f /*log2e/32*/ : 1.0f;
#pragma unroll
    for (int i = 0; i < 4; ++i)
#pragma unroll
      for (int j = 0; j < 4; ++j)
#pragma unroll
        for (int rg = 0; rg < 4; ++rg) {
          int row = m0 + wm + i * 16 + q * 4 + rg;
          int col = n0 + wn + j * 16 + r;
          float v = acc[i][j][rg];
          if (MODE == 0) {
            QK[(size_t)row * 2048 + col] = f2b(v * qscale);
          } else {
            v += bias[col] + resid[(size_t)row * N + col];
            Cf[(size_t)row * N + col] = v;
          }
        }
  }
}

// --- flash attention (no-max softmax): one block = (h, b, 128 q-rows),
// 4 waves x 32 rows. QK[8192][2048]: cols [0,1024)=Q (pre-scaled by
// log2e/32), [1024,2048)=K. Vt[1024][8192] pi-ordered per 64-token tile.
// R7: K-fragments read directly from global (K slice is L1/L2-resident and
// identical across the 4 waves) with a 1-tile register double-buffer.
// Only V is staged in LDS (pi order enables b128 PV reads); Ps holds P.
// NOTE: plain __launch_bounds__(256) — a min-waves 2nd arg made hipcc cap
// VGPR at 64 and spill the prefetch buffer (R6: WRITE_SIZE 1 GB).
__global__ __launch_bounds__(256) void attn_kernel(const unsigned short* __restrict__ QK,
                                                   const unsigned short* __restrict__ Vt,
                                                   unsigned short* __restrict__ O) {
  const int bx = blockIdx.x;
  const int qt = bx & 15, hb = bx >> 4;
  const int h = hb & 15, b = hb >> 4;
  const int tid = threadIdx.x, lane = tid & 63, w = tid >> 6;
  const int r = lane & 15, q = lane >> 4;

  __shared__ __align__(16) unsigned short Vst[64 * PAD];   // [dv][pi(key)]
  __shared__ __align__(16) unsigned short Ps[128 * PAD];   // [qrow][pi(key)]

  const size_t RS = 2048;
  const int l0 = qt * 128;

  short8 aq[2][2];
#pragma unroll
  for (int i = 0; i < 2; ++i) {
    const unsigned short* Qr =
        QK + (size_t)(b * 2048 + l0 + w * 32 + i * 16 + r) * RS + h * 64;
    aq[i][0] = *(const short8*)&Qr[q * 8];
    aq[i][1] = *(const short8*)&Qr[32 + q * 8];
  }

  // V staging maps: c = tid + rep*256, row = c>>3, off = (c&7)*8
  const int row0 = tid >> 3, off0 = (tid & 7) * 8;
  const int row1 = row0 + 32;
  const unsigned short* gV0 = Vt + (size_t)(h * 64 + row0) * 8192 + b * 2048 + off0;
  const unsigned short* gV1 = Vt + (size_t)(h * 64 + row1) * 8192 + b * 2048 + off0;
  unsigned short* lV0 = &Vst[row0 * PAD + off0];
  unsigned short* lV1 = &Vst[row1 * PAD + off0];

  // K direct-load base: lane (r,q), fragment (jn, half x):
  //   QK[(b*2048 + kt + jn*16 + r)*RS + 1024 + h*64 + x*32 + q*8]
  const unsigned short* gK = QK + (size_t)(b * 2048 + r) * RS + 1024 + h * 64 + q * 8;

  // prologue: stage V tile kt=0, load K frags kt=0
  uint4 vr0 = *(const uint4*)gV0;
  uint4 vr1 = *(const uint4*)gV1;
  short8 bk[4][2];
#pragma unroll
  for (int jn = 0; jn < 4; ++jn) {
    bk[jn][0] = *(const short8*)(gK + (size_t)(jn * 16) * RS);
    bk[jn][1] = *(const short8*)(gK + (size_t)(jn * 16) * RS + 32);
  }
  *(uint4*)lV0 = vr0;
  *(uint4*)lV1 = vr1;
  __syncthreads();

  float4v oacc[2][4] = {};
  float lsum[8] = {};

  for (int kt = 0; kt < 2048; kt += 64) {
    const bool has_next = (kt + 64) < 2048;
    // T14: issue next tile's global loads now; they land during compute
    short8 bkn[4][2];
    if (has_next) {
      vr0 = *(const uint4*)(gV0 + (kt + 64));
      vr1 = *(const uint4*)(gV1 + (kt + 64));
#pragma unroll
      for (int jn = 0; jn < 4; ++jn) {
        bkn[jn][0] = *(const short8*)(gK + (size_t)(kt + 64 + jn * 16) * RS);
        bkn[jn][1] = *(const short8*)(gK + (size_t)(kt + 64 + jn * 16) * RS + 32);
      }
    }

    // S = Q K^T (pre-scaled); exp2; accumulate lsum; pack P to LDS (pi order)
#pragma unroll
    for (int i = 0; i < 2; ++i) {
      float4v sacc[4];
      __builtin_amdgcn_s_setprio(1);
#pragma unroll
      for (int jn = 0; jn < 4; ++jn) {
        float4v z = {0.f, 0.f, 0.f, 0.f};
        z = MFMA(aq[i][0], bk[jn][0], z);
        z = MFMA(aq[i][1], bk[jn][1], z);
        sacc[jn] = z;
      }
      __builtin_amdgcn_s_setprio(0);
#pragma unroll
      for (int rg = 0; rg < 4; ++rg) {
        float p0 = fast_exp2(sacc[0][rg]);
        float p1 = fast_exp2(sacc[1][rg]);
        float p2 = fast_exp2(sacc[2][rg]);
        float p3 = fast_exp2(sacc[3][rg]);
        lsum[i * 4 + rg] += (p0 + p1) + (p2 + p3);
        // truncating bf16 pack: halfwords [pi=4r+0..3] = (p0,p1,p2,p3)
        uint2 pk;
        pk.x = __builtin_amdgcn_perm(fu(p1), fu(p0), 0x07060302u);
        pk.y = __builtin_amdgcn_perm(fu(p3), fu(p2), 0x07060302u);
        *(uint2*)&Ps[(w * 32 + i * 16 + q * 4 + rg) * PAD + r * 4] = pk;
      }
    }

    // V fragments: direct b128 reads (Vst already pi-ordered)
    short8 bv[4][2];
#pragma unroll
    for (int jv = 0; jv < 4; ++jv) {
      bv[jv][0] = *(const short8*)&Vst[(jv * 16 + r) * PAD + q * 8];
      bv[jv][1] = *(const short8*)&Vst[(jv * 16 + r) * PAD + 32 + q * 8];
    }

    // O += P V  (P A-frags are direct b128 reads in pi order)
#pragma unroll
    for (int i = 0; i < 2; ++i) {
      short8 ap0 = *(const short8*)&Ps[(w * 32 + i * 16 + r) * PAD + q * 8];
      short8 ap1 = *(const short8*)&Ps[(w * 32 + i * 16 + r) * PAD + 32 + q * 8];
      __builtin_amdgcn_s_setprio(1);
#pragma unroll
      for (int jv = 0; jv < 4; ++jv) {
        oacc[i][jv] = MFMA(ap0, bv[jv][0], oacc[i][jv]);
        oacc[i][jv] = MFMA(ap1, bv[jv][1], oacc[i][jv]);
      }
      __builtin_amdgcn_s_setprio(0);
    }

    // write next V tile into LDS after all waves finished reading current
    if (has_next) {
      __syncthreads();
      *(uint4*)lV0 = vr0;
      *(uint4*)lV1 = vr1;
      __syncthreads();
      // rotate K double-buffer (pure register renames)
#pragma unroll
      for (int jn = 0; jn < 4; ++jn) {
        bk[jn][0] = bkn[jn][0];
        bk[jn][1] = bkn[jn][1];
      }
    }
  }

  // one-time row-sum reduction across the 16 r-lanes
#pragma unroll
  for (int t = 0; t < 8; ++t)
#pragma unroll
    for (int d = 1; d < 16; d <<= 1) lsum[t] += __shfl_xor(lsum[t], d);

#pragma unroll
  for (int i = 0; i < 2; ++i)
#pragma unroll
    for (int jv = 0; jv < 4; ++jv)
#pragma unroll
      for (int rg = 0; rg < 4; ++rg) {
        int row = b * 2048 + l0 + w * 32 + i * 16 + q * 4 + rg;
        int col = h * 64 + jv * 16 + r;
        O[(size_t)row * 1024 + col] = f2b(oacc[i][jv][rg] / lsum[i * 4 + rg]);
      }
}

// --- row LayerNorm: mean, std(ddof=1), /(sigma+1e-3)*a + b  (all fp32)
__global__ __launch_bounds__(256) void ln_kernel(const float* __restrict__ Z,
                                                 const float* __restrict__ ga,
                                                 const float* __restrict__ be,
                                                 float* __restrict__ out) {
  const int row = blockIdx.x;
  const float* z = Z + (size_t)row * 1024;
  const int tid = threadIdx.x;
  float v[4], s = 0.f, sq = 0.f;
#pragma unroll
  for (int i = 0; i < 4; ++i) {
    v[i] = z[tid + i * 256];
    s += v[i];
    sq += v[i] * v[i];
  }
#pragma unroll
  for (int d = 1; d < 64; d <<= 1) { s += __shfl_xor(s, d); sq += __shfl_xor(sq, d); }
  __shared__ float ss[4], ssq[4];
  const int w = tid >> 6, lane = tid & 63;
  if (lane == 0) { ss[w] = s; ssq[w] = sq; }
  __syncthreads();
  s = ss[0] + ss[1] + ss[2] + ss[3];
  sq = ssq[0] + ssq[1] + ssq[2] + ssq[3];
  float mu = s * (1.f / 1024.f);
  float var = fmaxf((sq - 1024.f * mu * mu) * (1.f / 1023.f), 0.f);
  float inv = 1.f / (sqrtf(var) + 1e-3f);
#pragma unroll
  for (int i = 0; i < 4; ++i) {
    int c = tid + i * 256;
    out[(size_t)row * 1024 + c] = (v[i] - mu) * inv * ga[c] + be[c];
  }
}

extern "C" void kernel_launch(void* const* d_in, const int* in_sizes, int n_in,
                              void* d_out, int out_size, void* d_ws, size_t ws_size,
                              hipStream_t stream) {
  (void)in_sizes; (void)n_in; (void)out_size; (void)ws_size;
  const float* q      = (const float*)d_in[0];
  const float* w_qs   = (const float*)d_in[1];
  const float* w_ks   = (const float*)d_in[2];
  const float* w_vs   = (const float*)d_in[3];
  const float* proj_w = (const float*)d_in[4];
  const float* proj_b = (const float*)d_in[5];
  const float* ln_a   = (const float*)d_in[6];
  const float* ln_b   = (const float*)d_in[7];
  float* out = (float*)d_out;

  // ws (88 MB): [Qb 16MB][O 16MB][QK 32MB][Wt 6MB][Pb 2MB][Vt 16MB]
  // Z (fp32, 32MB) aliases QK (dead after attention).
  unsigned short* Qb  = (unsigned short*)d_ws;
  unsigned short* O   = Qb + (size_t)Mrows * Dm;
  unsigned short* QK  = O + (size_t)Mrows * Dm;
  unsigned short* Wt  = QK + (size_t)Mrows * 2048;
  unsigned short* Pb  = Wt + (size_t)NQKV * Dm;
  unsigned short* Vt  = Pb + (size_t)NP_ELEMS;
  float* Z = (float*)QK;

  conv_kernel<<<dim3((NQ_ELEMS + NP_ELEMS) / 256), dim3(256), 0, stream>>>(q, proj_w, Qb, Pb);
  repack_w<<<dim3(768), dim3(256), 0, stream>>>(w_qs, w_ks, w_vs, Wt);
  gemm_bt<0><<<dim3(NQKV / 128, Mrows / 128), dim3(256), 0, stream>>>(
      Qb, Wt, QK, Vt, nullptr, nullptr, nullptr, NQKV, Dm);
  attn_kernel<<<dim3(16 * NH * Bb), dim3(256), 0, stream>>>(QK, Vt, O);
  gemm_bt<1><<<dim3(Dm / 128, Mrows / 128), dim3(256), 0, stream>>>(
      O, Pb, nullptr, nullptr, Z, proj_b, q, Dm, Dm);
  ln_kernel<<<dim3(Mrows), dim3(256), 0, stream>>>(Z, ln_a, ln_b, out);
}

// Round 5
// 335.252 us; speedup vs baseline: 1.7789x; 1.1251x over previous
//
#include <hip/hip_runtime.h>
#include <hip/hip_bf16.h>
#include <cstdint>

// ---------------------------------------------------------------------------
// MultiHeadAttention (B=4, L=2048, d_model=1024, 16 heads, d_k=d_v=64)
// Inputs/outputs fp32. Internals: bf16 MFMA, fp32 accum.
// R2: V pre-transposed by QKV-GEMM epilogue; attn LDS stride 72.
// R3: no-max softmax (exp2, Q pre-scaled by log2e/32), deferred row-sum,
//     key-permuted P, 32 q-rows per wave.
// R4: pi-permutation moved into global Vt; GEMMs use global_load_lds w=16.
// R5: attn T14 async-STAGE split + T5 setprio around MFMA clusters.
// R6-R8 (FAILED, reverted): K-direct-from-global. With spill fixed (VGPR 100,
//     no scratch) it was STILL 164 vs 127.7 µs: per-wave scattered global K
//     loads (16 rows x 64B) + 4x duplicated K traffic on VMEM/L1 beat the
//     LDS savings. Cooperative LDS staging of wave-shared operands wins.
// R9: revert attn to R5 structure; add T1 XCD-aware block swizzles:
//     - attn: each XCD owns 8 full (h,b) groups -> K/V stay in its L2
//       (FETCH was 139MB vs ~48MB compulsory = cross-XCD duplication).
//     - gemms: logical tiles contiguous per XCD, x-fastest (A-panel reuse).
//     repack_w keeps the R6 LDS-transpose form.
// ---------------------------------------------------------------------------

typedef __attribute__((ext_vector_type(8))) short   short8;
typedef __attribute__((ext_vector_type(8))) __bf16  bf16x8;
typedef __attribute__((ext_vector_type(4))) float   float4v;

template <typename V>
__device__ __forceinline__ auto mfma_sel(V a, V b, float4v c, int)
    -> decltype(__builtin_amdgcn_mfma_f32_16x16x32_bf16(a, b, c, 0, 0, 0)) {
  return __builtin_amdgcn_mfma_f32_16x16x32_bf16(a, b, c, 0, 0, 0);
}
template <typename V>
__device__ __forceinline__ float4v mfma_sel(V a, V b, float4v c, long) {
  return __builtin_amdgcn_mfma_f32_16x16x32_bf16(
      __builtin_bit_cast(bf16x8, a), __builtin_bit_cast(bf16x8, b), c, 0, 0, 0);
}
__device__ __forceinline__ float4v MFMA(short8 a, short8 b, float4v c) {
  return mfma_sel(a, b, c, 0);
}

__device__ __forceinline__ unsigned short f2b(float f) {
  union { float f; unsigned int u; } x; x.f = f;
  unsigned int r = x.u + 0x7FFFu + ((x.u >> 16) & 1u);  // RNE
  return (unsigned short)(r >> 16);
}
__device__ __forceinline__ unsigned int fu(float f) {
  union { float f; unsigned int u; } x; x.f = f; return x.u;
}
__device__ __forceinline__ float fast_exp2(float x) {
#if __has_builtin(__builtin_amdgcn_exp2f)
  return __builtin_amdgcn_exp2f(x);
#else
  return exp2f(x);
#endif
}

// async global->LDS, 16B per lane; LDS dest = wave-uniform base + lane*16
__device__ __forceinline__ void async_cp16(const unsigned short* g, unsigned short* l) {
  __builtin_amdgcn_global_load_lds(
      (const __attribute__((address_space(1))) void*)g,
      (__attribute__((address_space(3))) void*)l, 16, 0, 0);
}

constexpr int Bb = 4, Ls = 2048, Dm = 1024, NH = 16;
constexpr int Mrows = Bb * Ls;          // 8192
constexpr int NQKV = 3 * Dm;            // 3072
constexpr int NQ_ELEMS = Mrows * Dm;    // 8388608
constexpr int NP_ELEMS = Dm * Dm;       // 1048576
constexpr int PAD = 72;                 // LDS row stride (halfwords), 144B

// --- fp32 -> bf16 conversion for q (8M) and proj_w (1M)
__global__ __launch_bounds__(256) void conv_kernel(const float* __restrict__ q,
                                                   const float* __restrict__ pw,
                                                   unsigned short* __restrict__ Qb,
                                                   unsigned short* __restrict__ Pb) {
  int idx = blockIdx.x * 256 + threadIdx.x;  // 9437184 total
  if (idx < NQ_ELEMS) Qb[idx] = f2b(q[idx]);
  else                Pb[idx - NQ_ELEMS] = f2b(pw[idx - NQ_ELEMS]);
}

// --- repack fp32 w_qs/w_ks/w_vs [16][1024][64] -> bf16 Wt[3072][1024]
// LDS-transpose: reads lane-contiguous over kk, writes vectorized 32B/thread.
__global__ __launch_bounds__(256) void repack_w(const float* __restrict__ wq,
                                                const float* __restrict__ wk,
                                                const float* __restrict__ wv,
                                                unsigned short* __restrict__ Wt) {
  const int bid = blockIdx.x;          // 768 blocks
  const int which = bid >> 8;          // 0,1,2
  const int h = (bid >> 4) & 15, dt = bid & 15;
  const float* w = (which == 0) ? wq : (which == 1 ? wk : wv);

  __shared__ float tile[64][65];
  const int kk = threadIdx.x & 63, dd = threadIdx.x >> 6;  // 4 rows/pass
#pragma unroll
  for (int p = 0; p < 16; ++p) {
    int d = dt * 64 + p * 4 + dd;
    tile[p * 4 + dd][kk] = w[(size_t)(h * 1024 + d) * 64 + kk];
  }
  __syncthreads();
  const int kkw = threadIdx.x >> 2, c0 = (threadIdx.x & 3) * 16;
  unsigned short tmp[16];
#pragma unroll
  for (int j = 0; j < 16; ++j) tmp[j] = f2b(tile[c0 + j][kkw]);
  unsigned short* dst =
      Wt + (size_t)(which * 1024 + h * 64 + kkw) * 1024 + dt * 64 + c0;
  *(uint4*)&dst[0] = *(const uint4*)&tmp[0];
  *(uint4*)&dst[8] = *(const uint4*)&tmp[8];
}

// --- C = A[M][K] * Bt[N][K]^T (bf16), 128x128 tile, BK=32, 4 waves 64x64,
// async global_load_lds width-16 staging. T1 XCD swizzle on tile ids.
// MODE 0 (QKV): cols<1024 -> Q scaled by log2e/32 -> QK; [1024,2048) -> K
//   -> QK. cols>=2048 -> V stored pi-ordered into Vt[dv][8192]:
//   Vt[dv][64*(t/64) + pi(t%64)], pi(16*jn+r) = 4*r+jn. Each lane holds the
//   16 values for 16 contiguous pi-positions [16q,16q+16): p=16q+4*rg+i.
// MODE 1 (proj): +bias(f32) +residual(f32), store fp32 Cf[row*N+col].
template <int MODE>
__global__ __launch_bounds__(256) void gemm_bt(const unsigned short* __restrict__ A,
                                               const unsigned short* __restrict__ Bt,
                                               unsigned short* __restrict__ QK,
                                               unsigned short* __restrict__ Vt,
                                               float* __restrict__ Cf,
                                               const float* __restrict__ bias,
                                               const float* __restrict__ resid,
                                               int N, int K) {
  __shared__ __align__(16) unsigned short As[128 * 32];
  __shared__ __align__(16) unsigned short Bs[128 * 32];
  const int tid = threadIdx.x;
  const int lane = tid & 63, w = tid >> 6;
  const int wm = (w >> 1) * 64, wn = (w & 1) * 64;

  // T1: raw wg -> XCD-contiguous logical tile (nwg % 8 == 0 for both modes)
  const int Nx = gridDim.x;
  const int cpx = (Nx * gridDim.y) >> 3;
  const int wg = blockIdx.y * Nx + blockIdx.x;
  const int lg = (wg & 7) * cpx + (wg >> 3);
  const int m0 = (lg / Nx) * 128, n0 = (lg % Nx) * 128;
  const int r = lane & 15, q = lane >> 4;

  // staging maps: issue covers 64 rows; wave w covers rows 16w..16w+16
  const unsigned short* gA = A + (size_t)(m0 + 16 * w + (lane >> 2)) * K + (lane & 3) * 8;
  const unsigned short* gB = Bt + (size_t)(n0 + 16 * w + (lane >> 2)) * K + (lane & 3) * 8;
  unsigned short* lA0 = As + 16 * w * 32;
  unsigned short* lA1 = As + (64 + 16 * w) * 32;
  unsigned short* lB0 = Bs + 16 * w * 32;
  unsigned short* lB1 = Bs + (64 + 16 * w) * 32;

  float4v acc[4][4] = {};

  for (int k0 = 0; k0 < K; k0 += 32) {
    async_cp16(gA + k0, lA0);
    async_cp16(gA + (size_t)64 * K + k0, lA1);
    async_cp16(gB + k0, lB0);
    async_cp16(gB + (size_t)64 * K + k0, lB1);
    __syncthreads();
    short8 af[4], bfr[4];
#pragma unroll
    for (int i = 0; i < 4; ++i)
      af[i] = *(const short8*)&As[(wm + i * 16 + r) * 32 + q * 8];
#pragma unroll
    for (int j = 0; j < 4; ++j)
      bfr[j] = *(const short8*)&Bs[(wn + j * 16 + r) * 32 + q * 8];
#pragma unroll
    for (int i = 0; i < 4; ++i)
#pragma unroll
      for (int j = 0; j < 4; ++j)
        acc[i][j] = MFMA(af[i], bfr[j], acc[i][j]);
    __syncthreads();
  }

  if (MODE == 0 && n0 >= 2048) {
    // pi-ordered V: lane writes positions [16q, 16q+16) of token-tile m0+wm
#pragma unroll
    for (int j = 0; j < 4; ++j) {
      int dv = n0 + wn + j * 16 + r - 2048;
      unsigned short t16[16];
#pragma unroll
      for (int i = 0; i < 4; ++i)
#pragma unroll
        for (int rg = 0; rg < 4; ++rg)
          t16[4 * rg + i] = f2b(acc[i][j][rg]);
      unsigned short* dst = Vt + (size_t)dv * 8192 + (m0 + wm) + 16 * q;
      *(uint4*)&dst[0] = *(const uint4*)&t16[0];
      *(uint4*)&dst[8] = *(const uint4*)&t16[8];
    }
  } else {
    const float qscale = (MODE == 0 && n0 < 1024) ? 0.045084230f /*log2e/32*/ : 1.0f;
#pragma unroll
    for (int i = 0; i < 4; ++i)
#pragma unroll
      for (int j = 0; j < 4; ++j)
#pragma unroll
        for (int rg = 0; rg < 4; ++rg) {
          int row = m0 + wm + i * 16 + q * 4 + rg;
          int col = n0 + wn + j * 16 + r;
          float v = acc[i][j][rg];
          if (MODE == 0) {
            QK[(size_t)row * 2048 + col] = f2b(v * qscale);
          } else {
            v += bias[col] + resid[(size_t)row * N + col];
            Cf[(size_t)row * N + col] = v;
          }
        }
  }
}

// --- flash attention (no-max softmax): one block = (h, b, 128 q-rows),
// 4 waves x 32 rows. QK[8192][2048]: cols [0,1024)=Q (pre-scaled by
// log2e/32), [1024,2048)=K. Vt[1024][8192] pi-ordered per 64-token tile.
// P stored to LDS at pi(key)=4r+jn (b64 writes); both P A-frags and V
// B-frags are direct b128 reads in pi order.
// R5 structure: T14 async-STAGE split (next K/V tile -> regs at loop top,
// LDS write after barrier) + T5 setprio.
// R9: T1 swizzle — XCD x owns (h,b) groups [8x, 8x+8), 16 qt-tiles each,
// so each XCD's L2 keeps its K/V slices resident.
__global__ __launch_bounds__(256) void attn_kernel(const unsigned short* __restrict__ QK,
                                                   const unsigned short* __restrict__ Vt,
                                                   unsigned short* __restrict__ O) {
  const int bx = blockIdx.x;
  // T1: logical = (bx%8)*128 + bx/8; hb = logical/16, qt = logical%16
  const int lg = (bx & 7) * 128 + (bx >> 3);
  const int qt = lg & 15, hb = lg >> 4;
  const int h = hb & 15, b = hb >> 4;
  const int tid = threadIdx.x, lane = tid & 63, w = tid >> 6;
  const int r = lane & 15, q = lane >> 4;

  __shared__ __align__(16) unsigned short Ks[64 * PAD];    // [key][d]
  __shared__ __align__(16) unsigned short Vst[64 * PAD];   // [dv][pi(key)]
  __shared__ __align__(16) unsigned short Ps[128 * PAD];   // [qrow][pi(key)]

  const size_t RS = 2048;
  const int l0 = qt * 128;

  short8 aq[2][2];
#pragma unroll
  for (int i = 0; i < 2; ++i) {
    const unsigned short* Qr =
        QK + (size_t)(b * 2048 + l0 + w * 32 + i * 16 + r) * RS + h * 64;
    aq[i][0] = *(const short8*)&Qr[q * 8];
    aq[i][1] = *(const short8*)&Qr[32 + q * 8];
  }

  // staging maps: c = tid + rep*256, row = c>>3, off = (c&7)*8
  const int row0 = tid >> 3, off0 = (tid & 7) * 8;
  const int row1 = row0 + 32;               // (tid+256)>>3, same off
  const unsigned short* gK0 = QK + (size_t)(b * 2048 + row0) * RS + 1024 + h * 64 + off0;
  const unsigned short* gK1 = QK + (size_t)(b * 2048 + row1) * RS + 1024 + h * 64 + off0;
  const unsigned short* gV0 = Vt + (size_t)(h * 64 + row0) * 8192 + b * 2048 + off0;
  const unsigned short* gV1 = Vt + (size_t)(h * 64 + row1) * 8192 + b * 2048 + off0;
  unsigned short* lK0 = &Ks[row0 * PAD + off0];
  unsigned short* lK1 = &Ks[row1 * PAD + off0];
  unsigned short* lV0 = &Vst[row0 * PAD + off0];
  unsigned short* lV1 = &Vst[row1 * PAD + off0];

  // prologue: stage tile kt=0
  uint4 kr0 = *(const uint4*)gK0;
  uint4 kr1 = *(const uint4*)gK1;
  uint4 vr0 = *(const uint4*)gV0;
  uint4 vr1 = *(const uint4*)gV1;
  *(uint4*)lK0 = kr0; *(uint4*)lK1 = kr1;
  *(uint4*)lV0 = vr0; *(uint4*)lV1 = vr1;
  __syncthreads();

  float4v oacc[2][4] = {};
  float lsum[8] = {};

  for (int kt = 0; kt < 2048; kt += 64) {
    const bool has_next = (kt + 64) < 2048;
    // T14: issue next tile's global loads now; they land during compute
    if (has_next) {
      kr0 = *(const uint4*)(gK0 + (size_t)(kt + 64) * RS);
      kr1 = *(const uint4*)(gK1 + (size_t)(kt + 64) * RS);
      vr0 = *(const uint4*)(gV0 + (kt + 64));
      vr1 = *(const uint4*)(gV1 + (kt + 64));
    }

    // K fragments (shared across both i row-blocks)
    short8 bk[4][2];
#pragma unroll
    for (int jn = 0; jn < 4; ++jn) {
      bk[jn][0] = *(const short8*)&Ks[(jn * 16 + r) * PAD + q * 8];
      bk[jn][1] = *(const short8*)&Ks[(jn * 16 + r) * PAD + 32 + q * 8];
    }

    // S = Q K^T (pre-scaled); exp2; accumulate lsum; pack P to LDS (pi order)
#pragma unroll
    for (int i = 0; i < 2; ++i) {
      float4v sacc[4];
      __builtin_amdgcn_s_setprio(1);
#pragma unroll
      for (int jn = 0; jn < 4; ++jn) {
        float4v z = {0.f, 0.f, 0.f, 0.f};
        z = MFMA(aq[i][0], bk[jn][0], z);
        z = MFMA(aq[i][1], bk[jn][1], z);
        sacc[jn] = z;
      }
      __builtin_amdgcn_s_setprio(0);
#pragma unroll
      for (int rg = 0; rg < 4; ++rg) {
        float p0 = fast_exp2(sacc[0][rg]);
        float p1 = fast_exp2(sacc[1][rg]);
        float p2 = fast_exp2(sacc[2][rg]);
        float p3 = fast_exp2(sacc[3][rg]);
        lsum[i * 4 + rg] += (p0 + p1) + (p2 + p3);
        // truncating bf16 pack: halfwords [pi=4r+0..3] = (p0,p1,p2,p3)
        uint2 pk;
        pk.x = __builtin_amdgcn_perm(fu(p1), fu(p0), 0x07060302u);
        pk.y = __builtin_amdgcn_perm(fu(p3), fu(p2), 0x07060302u);
        *(uint2*)&Ps[(w * 32 + i * 16 + q * 4 + rg) * PAD + r * 4] = pk;
      }
    }

    // V fragments: direct b128 reads (Vst already pi-ordered)
    short8 bv[4][2];
#pragma unroll
    for (int jv = 0; jv < 4; ++jv) {
      bv[jv][0] = *(const short8*)&Vst[(jv * 16 + r) * PAD + q * 8];
      bv[jv][1] = *(const short8*)&Vst[(jv * 16 + r) * PAD + 32 + q * 8];
    }

    // O += P V  (P A-frags are direct b128 reads in pi order)
#pragma unroll
    for (int i = 0; i < 2; ++i) {
      short8 ap0 = *(const short8*)&Ps[(w * 32 + i * 16 + r) * PAD + q * 8];
      short8 ap1 = *(const short8*)&Ps[(w * 32 + i * 16 + r) * PAD + 32 + q * 8];
      __builtin_amdgcn_s_setprio(1);
#pragma unroll
      for (int jv = 0; jv < 4; ++jv) {
        oacc[i][jv] = MFMA(ap0, bv[jv][0], oacc[i][jv]);
        oacc[i][jv] = MFMA(ap1, bv[jv][1], oacc[i][jv]);
      }
      __builtin_amdgcn_s_setprio(0);
    }

    // write next tile into LDS after all waves finished reading current one
    if (has_next) {
      __syncthreads();
      *(uint4*)lK0 = kr0; *(uint4*)lK1 = kr1;
      *(uint4*)lV0 = vr0; *(uint4*)lV1 = vr1;
      __syncthreads();
    }
  }

  // one-time row-sum reduction across the 16 r-lanes
#pragma unroll
  for (int t = 0; t < 8; ++t)
#pragma unroll
    for (int d = 1; d < 16; d <<= 1) lsum[t] += __shfl_xor(lsum[t], d);

#pragma unroll
  for (int i = 0; i < 2; ++i)
#pragma unroll
    for (int jv = 0; jv < 4; ++jv)
#pragma unroll
      for (int rg = 0; rg < 4; ++rg) {
        int row = b * 2048 + l0 + w * 32 + i * 16 + q * 4 + rg;
        int col = h * 64 + jv * 16 + r;
        O[(size_t)row * 1024 + col] = f2b(oacc[i][jv][rg] / lsum[i * 4 + rg]);
      }
}

// --- row LayerNorm: mean, std(ddof=1), /(sigma+1e-3)*a + b  (all fp32)
__global__ __launch_bounds__(256) void ln_kernel(const float* __restrict__ Z,
                                                 const float* __restrict__ ga,
                                                 const float* __restrict__ be,
                                                 float* __restrict__ out) {
  const int row = blockIdx.x;
  const float* z = Z + (size_t)row * 1024;
  const int tid = threadIdx.x;
  float v[4], s = 0.f, sq = 0.f;
#pragma unroll
  for (int i = 0; i < 4; ++i) {
    v[i] = z[tid + i * 256];
    s += v[i];
    sq += v[i] * v[i];
  }
#pragma unroll
  for (int d = 1; d < 64; d <<= 1) { s += __shfl_xor(s, d); sq += __shfl_xor(sq, d); }
  __shared__ float ss[4], ssq[4];
  const int w = tid >> 6, lane = tid & 63;
  if (lane == 0) { ss[w] = s; ssq[w] = sq; }
  __syncthreads();
  s = ss[0] + ss[1] + ss[2] + ss[3];
  sq = ssq[0] + ssq[1] + ssq[2] + ssq[3];
  float mu = s * (1.f / 1024.f);
  float var = fmaxf((sq - 1024.f * mu * mu) * (1.f / 1023.f), 0.f);
  float inv = 1.f / (sqrtf(var) + 1e-3f);
#pragma unroll
  for (int i = 0; i < 4; ++i) {
    int c = tid + i * 256;
    out[(size_t)row * 1024 + c] = (v[i] - mu) * inv * ga[c] + be[c];
  }
}

extern "C" void kernel_launch(void* const* d_in, const int* in_sizes, int n_in,
                              void* d_out, int out_size, void* d_ws, size_t ws_size,
                              hipStream_t stream) {
  (void)in_sizes; (void)n_in; (void)out_size; (void)ws_size;
  const float* q      = (const float*)d_in[0];
  const float* w_qs   = (const float*)d_in[1];
  const float* w_ks   = (const float*)d_in[2];
  const float* w_vs   = (const float*)d_in[3];
  const float* proj_w = (const float*)d_in[4];
  const float* proj_b = (const float*)d_in[5];
  const float* ln_a   = (const float*)d_in[6];
  const float* ln_b   = (const float*)d_in[7];
  float* out = (float*)d_out;

  // ws (88 MB): [Qb 16MB][O 16MB][QK 32MB][Wt 6MB][Pb 2MB][Vt 16MB]
  // Z (fp32, 32MB) aliases QK (dead after attention).
  unsigned short* Qb  = (unsigned short*)d_ws;
  unsigned short* O   = Qb + (size_t)Mrows * Dm;
  unsigned short* QK  = O + (size_t)Mrows * Dm;
  unsigned short* Wt  = QK + (size_t)Mrows * 2048;
  unsigned short* Pb  = Wt + (size_t)NQKV * Dm;
  unsigned short* Vt  = Pb + (size_t)NP_ELEMS;
  float* Z = (float*)QK;

  conv_kernel<<<dim3((NQ_ELEMS + NP_ELEMS) / 256), dim3(256), 0, stream>>>(q, proj_w, Qb, Pb);
  repack_w<<<dim3(768), dim3(256), 0, stream>>>(w_qs, w_ks, w_vs, Wt);
  gemm_bt<0><<<dim3(NQKV / 128, Mrows / 128), dim3(256), 0, stream>>>(
      Qb, Wt, QK, Vt, nullptr, nullptr, nullptr, NQKV, Dm);
  attn_kernel<<<dim3(16 * NH * Bb), dim3(256), 0, stream>>>(QK, Vt, O);
  gemm_bt<1><<<dim3(Dm / 128, Mrows / 128), dim3(256), 0, stream>>>(
      O, Pb, nullptr, nullptr, Z, proj_b, q, Dm, Dm);
  ln_kernel<<<dim3(Mrows), dim3(256), 0, stream>>>(Z, ln_a, ln_b, out);
}

// Round 6
// 310.991 us; speedup vs baseline: 1.9177x; 1.0780x over previous
//
#include <hip/hip_runtime.h>
#include <hip/hip_bf16.h>
#include <cstdint>

// ---------------------------------------------------------------------------
// MultiHeadAttention (B=4, L=2048, d_model=1024, 16 heads, d_k=d_v=64)
// Inputs/outputs fp32. Internals: bf16 MFMA, fp32 accum.
// R2-R5: V pre-transposed; no-max softmax (exp2, pre-scaled Q); pi-ordered Vt;
//     attn T14 async-STAGE + T5 setprio.
// R6-R8 (FAILED, reverted): attn K-direct-from-global (VMEM re-read worse
//     than cooperative LDS staging even when L2-resident).
// R9: T1 XCD swizzles. attn FETCH 139->24.6MB but dur only -4% (latency was
//     mostly hidden); attn now ~563 TF, trans-pipe floor ~54us. GEMMs+gaps
//     (~185us) now dominate non-attn time.
// R10: GEMM BK 32->64 (halves the per-iteration vmcnt-drain stalls of the
//     2-barrier structure; LDS 32KB keeps 3 blocks/CU) + XOR-swizzled LDS
//     via pre-swizzled global source (fixes the pre-existing 8-way and the
//     would-be 16-way fragment-read conflict; rule-21 both-sides involution).
//     conv+repack fused into prep_kernel (one fewer launch).
// ---------------------------------------------------------------------------

typedef __attribute__((ext_vector_type(8))) short   short8;
typedef __attribute__((ext_vector_type(8))) __bf16  bf16x8;
typedef __attribute__((ext_vector_type(4))) float   float4v;

template <typename V>
__device__ __forceinline__ auto mfma_sel(V a, V b, float4v c, int)
    -> decltype(__builtin_amdgcn_mfma_f32_16x16x32_bf16(a, b, c, 0, 0, 0)) {
  return __builtin_amdgcn_mfma_f32_16x16x32_bf16(a, b, c, 0, 0, 0);
}
template <typename V>
__device__ __forceinline__ float4v mfma_sel(V a, V b, float4v c, long) {
  return __builtin_amdgcn_mfma_f32_16x16x32_bf16(
      __builtin_bit_cast(bf16x8, a), __builtin_bit_cast(bf16x8, b), c, 0, 0, 0);
}
__device__ __forceinline__ float4v MFMA(short8 a, short8 b, float4v c) {
  return mfma_sel(a, b, c, 0);
}

__device__ __forceinline__ unsigned short f2b(float f) {
  union { float f; unsigned int u; } x; x.f = f;
  unsigned int r = x.u + 0x7FFFu + ((x.u >> 16) & 1u);  // RNE
  return (unsigned short)(r >> 16);
}
__device__ __forceinline__ unsigned int fu(float f) {
  union { float f; unsigned int u; } x; x.f = f; return x.u;
}
__device__ __forceinline__ float fast_exp2(float x) {
#if __has_builtin(__builtin_amdgcn_exp2f)
  return __builtin_amdgcn_exp2f(x);
#else
  return exp2f(x);
#endif
}

// async global->LDS, 16B per lane; LDS dest = wave-uniform base + lane*16
__device__ __forceinline__ void async_cp16(const unsigned short* g, unsigned short* l) {
  __builtin_amdgcn_global_load_lds(
      (const __attribute__((address_space(1))) void*)g,
      (__attribute__((address_space(3))) void*)l, 16, 0, 0);
}

constexpr int Bb = 4, Ls = 2048, Dm = 1024, NH = 16;
constexpr int Mrows = Bb * Ls;          // 8192
constexpr int NQKV = 3 * Dm;            // 3072
constexpr int NQ_ELEMS = Mrows * Dm;    // 8388608
constexpr int NP_ELEMS = Dm * Dm;       // 1048576
constexpr int PAD = 72;                 // attn LDS row stride (halfwords)
constexpr int NCONV = (NQ_ELEMS + NP_ELEMS) / 256;  // 36864 conv blocks

// --- fused prep: fp32->bf16 conv of q (8M) + proj_w (1M), and LDS-transpose
// repack of w_qs/w_ks/w_vs [16][1024][64] -> bf16 Wt[3072][1024].
__global__ __launch_bounds__(256) void prep_kernel(const float* __restrict__ q,
                                                   const float* __restrict__ pw,
                                                   const float* __restrict__ wq,
                                                   const float* __restrict__ wk,
                                                   const float* __restrict__ wv,
                                                   unsigned short* __restrict__ Qb,
                                                   unsigned short* __restrict__ Pb,
                                                   unsigned short* __restrict__ Wt) {
  const int bid = blockIdx.x;
  if (bid < NCONV) {
    int idx = bid * 256 + threadIdx.x;
    if (idx < NQ_ELEMS) Qb[idx] = f2b(q[idx]);
    else                Pb[idx - NQ_ELEMS] = f2b(pw[idx - NQ_ELEMS]);
    return;
  }
  // repack path: 768 blocks
  const int rb = bid - NCONV;
  const int which = rb >> 8;           // 0,1,2
  const int h = (rb >> 4) & 15, dt = rb & 15;
  const float* w = (which == 0) ? wq : (which == 1 ? wk : wv);

  __shared__ float tile[64][65];
  const int kk = threadIdx.x & 63, dd = threadIdx.x >> 6;  // 4 rows/pass
#pragma unroll
  for (int p = 0; p < 16; ++p) {
    int d = dt * 64 + p * 4 + dd;
    tile[p * 4 + dd][kk] = w[(size_t)(h * 1024 + d) * 64 + kk];
  }
  __syncthreads();
  const int kkw = threadIdx.x >> 2, c0 = (threadIdx.x & 3) * 16;
  unsigned short tmp[16];
#pragma unroll
  for (int j = 0; j < 16; ++j) tmp[j] = f2b(tile[c0 + j][kkw]);
  unsigned short* dst =
      Wt + (size_t)(which * 1024 + h * 64 + kkw) * 1024 + dt * 64 + c0;
  *(uint4*)&dst[0] = *(const uint4*)&tmp[0];
  *(uint4*)&dst[8] = *(const uint4*)&tmp[8];
}

// --- C = A[M][K] * Bt[N][K]^T (bf16), 128x128 tile, BK=64, 4 waves 64x64,
// async global_load_lds width-16 staging, T1 XCD swizzle.
// LDS layout [row][64] with 16B-slot XOR swizzle: physical slot =
// (logical col8) ^ (row&7). Staging keeps LDS linear and pre-swizzles the
// GLOBAL source column (permutation stays inside a 128B segment ->
// coalescing preserved); fragment reads apply the same XOR.
// MODE 0 (QKV): cols<1024 -> Q scaled by log2e/32 -> QK; [1024,2048) -> K
//   -> QK. cols>=2048 -> V stored pi-ordered into Vt[dv][8192].
// MODE 1 (proj): +bias(f32) +residual(f32), store fp32 Cf[row*N+col].
template <int MODE>
__global__ __launch_bounds__(256) void gemm_bt(const unsigned short* __restrict__ A,
                                               const unsigned short* __restrict__ Bt,
                                               unsigned short* __restrict__ QK,
                                               unsigned short* __restrict__ Vt,
                                               float* __restrict__ Cf,
                                               const float* __restrict__ bias,
                                               const float* __restrict__ resid,
                                               int N, int K) {
  __shared__ __align__(16) unsigned short As[128 * 64];
  __shared__ __align__(16) unsigned short Bs[128 * 64];
  const int tid = threadIdx.x;
  const int lane = tid & 63, w = tid >> 6;
  const int wm = (w >> 1) * 64, wn = (w & 1) * 64;

  // T1: raw wg -> XCD-contiguous logical tile (nwg % 8 == 0 for both modes)
  const int Nx = gridDim.x;
  const int cpx = (Nx * gridDim.y) >> 3;
  const int wg = blockIdx.y * Nx + blockIdx.x;
  const int lg = (wg & 7) * cpx + (wg >> 3);
  const int m0 = (lg / Nx) * 128, n0 = (lg % Nx) * 128;
  const int r = lane & 15, q = lane >> 4;

  // staging maps: call c stages rows 32c..32c+31; thread covers row
  // 8w + (lane>>3); global col8 pre-swizzled by row&7 = (lane>>3)&7.
  const int srow = 8 * w + (lane >> 3);
  const int scol = ((lane & 7) ^ ((lane >> 3) & 7)) * 8;
  const unsigned short* gA = A + (size_t)(m0 + srow) * K + scol;
  const unsigned short* gB = Bt + (size_t)(n0 + srow) * K + scol;
  unsigned short* lA = As + w * 512;  // wave-uniform base (hw units)
  unsigned short* lB = Bs + w * 512;

  float4v acc[4][4] = {};

  for (int k0 = 0; k0 < K; k0 += 64) {
#pragma unroll
    for (int c = 0; c < 4; ++c) {
      async_cp16(gA + (size_t)(32 * c) * K + k0, lA + c * 2048);
      async_cp16(gB + (size_t)(32 * c) * K + k0, lB + c * 2048);
    }
    __syncthreads();
#pragma unroll
    for (int ks = 0; ks < 2; ++ks) {
      short8 af[4], bfr[4];
#pragma unroll
      for (int i = 0; i < 4; ++i)
        af[i] = *(const short8*)&As[(wm + i * 16 + r) * 64 +
                                    (((ks << 2) + q) ^ (r & 7)) * 8];
#pragma unroll
      for (int j = 0; j < 4; ++j)
        bfr[j] = *(const short8*)&Bs[(wn + j * 16 + r) * 64 +
                                     (((ks << 2) + q) ^ (r & 7)) * 8];
#pragma unroll
      for (int i = 0; i < 4; ++i)
#pragma unroll
        for (int j = 0; j < 4; ++j)
          acc[i][j] = MFMA(af[i], bfr[j], acc[i][j]);
    }
    __syncthreads();
  }

  if (MODE == 0 && n0 >= 2048) {
    // pi-ordered V: lane writes positions [16q, 16q+16) of token-tile m0+wm
#pragma unroll
    for (int j = 0; j < 4; ++j) {
      int dv = n0 + wn + j * 16 + r - 2048;
      unsigned short t16[16];
#pragma unroll
      for (int i = 0; i < 4; ++i)
#pragma unroll
        for (int rg = 0; rg < 4; ++rg)
          t16[4 * rg + i] = f2b(acc[i][j][rg]);
      unsigned short* dst = Vt + (size_t)dv * 8192 + (m0 + wm) + 16 * q;
      *(uint4*)&dst[0] = *(const uint4*)&t16[0];
      *(uint4*)&dst[8] = *(const uint4*)&t16[8];
    }
  } else {
    const float qscale = (MODE == 0 && n0 < 1024) ? 0.045084230f /*log2e/32*/ : 1.0f;
#pragma unroll
    for (int i = 0; i < 4; ++i)
#pragma unroll
      for (int j = 0; j < 4; ++j)
#pragma unroll
        for (int rg = 0; rg < 4; ++rg) {
          int row = m0 + wm + i * 16 + q * 4 + rg;
          int col = n0 + wn + j * 16 + r;
          float v = acc[i][j][rg];
          if (MODE == 0) {
            QK[(size_t)row * 2048 + col] = f2b(v * qscale);
          } else {
            v += bias[col] + resid[(size_t)row * N + col];
            Cf[(size_t)row * N + col] = v;
          }
        }
  }
}

// --- flash attention (no-max softmax): one block = (h, b, 128 q-rows),
// 4 waves x 32 rows. QK[8192][2048]: cols [0,1024)=Q (pre-scaled by
// log2e/32), [1024,2048)=K. Vt[1024][8192] pi-ordered per 64-token tile.
// T14 async-STAGE split + T5 setprio; T1 XCD swizzle (R9).
__global__ __launch_bounds__(256) void attn_kernel(const unsigned short* __restrict__ QK,
                                                   const unsigned short* __restrict__ Vt,
                                                   unsigned short* __restrict__ O) {
  const int bx = blockIdx.x;
  // T1: logical = (bx%8)*128 + bx/8; hb = logical/16, qt = logical%16
  const int lg = (bx & 7) * 128 + (bx >> 3);
  const int qt = lg & 15, hb = lg >> 4;
  const int h = hb & 15, b = hb >> 4;
  const int tid = threadIdx.x, lane = tid & 63, w = tid >> 6;
  const int r = lane & 15, q = lane >> 4;

  __shared__ __align__(16) unsigned short Ks[64 * PAD];    // [key][d]
  __shared__ __align__(16) unsigned short Vst[64 * PAD];   // [dv][pi(key)]
  __shared__ __align__(16) unsigned short Ps[128 * PAD];   // [qrow][pi(key)]

  const size_t RS = 2048;
  const int l0 = qt * 128;

  short8 aq[2][2];
#pragma unroll
  for (int i = 0; i < 2; ++i) {
    const unsigned short* Qr =
        QK + (size_t)(b * 2048 + l0 + w * 32 + i * 16 + r) * RS + h * 64;
    aq[i][0] = *(const short8*)&Qr[q * 8];
    aq[i][1] = *(const short8*)&Qr[32 + q * 8];
  }

  // staging maps: c = tid + rep*256, row = c>>3, off = (c&7)*8
  const int row0 = tid >> 3, off0 = (tid & 7) * 8;
  const int row1 = row0 + 32;               // (tid+256)>>3, same off
  const unsigned short* gK0 = QK + (size_t)(b * 2048 + row0) * RS + 1024 + h * 64 + off0;
  const unsigned short* gK1 = QK + (size_t)(b * 2048 + row1) * RS + 1024 + h * 64 + off0;
  const unsigned short* gV0 = Vt + (size_t)(h * 64 + row0) * 8192 + b * 2048 + off0;
  const unsigned short* gV1 = Vt + (size_t)(h * 64 + row1) * 8192 + b * 2048 + off0;
  unsigned short* lK0 = &Ks[row0 * PAD + off0];
  unsigned short* lK1 = &Ks[row1 * PAD + off0];
  unsigned short* lV0 = &Vst[row0 * PAD + off0];
  unsigned short* lV1 = &Vst[row1 * PAD + off0];

  // prologue: stage tile kt=0
  uint4 kr0 = *(const uint4*)gK0;
  uint4 kr1 = *(const uint4*)gK1;
  uint4 vr0 = *(const uint4*)gV0;
  uint4 vr1 = *(const uint4*)gV1;
  *(uint4*)lK0 = kr0; *(uint4*)lK1 = kr1;
  *(uint4*)lV0 = vr0; *(uint4*)lV1 = vr1;
  __syncthreads();

  float4v oacc[2][4] = {};
  float lsum[8] = {};

  for (int kt = 0; kt < 2048; kt += 64) {
    const bool has_next = (kt + 64) < 2048;
    // T14: issue next tile's global loads now; they land during compute
    if (has_next) {
      kr0 = *(const uint4*)(gK0 + (size_t)(kt + 64) * RS);
      kr1 = *(const uint4*)(gK1 + (size_t)(kt + 64) * RS);
      vr0 = *(const uint4*)(gV0 + (kt + 64));
      vr1 = *(const uint4*)(gV1 + (kt + 64));
    }

    // K fragments (shared across both i row-blocks)
    short8 bk[4][2];
#pragma unroll
    for (int jn = 0; jn < 4; ++jn) {
      bk[jn][0] = *(const short8*)&Ks[(jn * 16 + r) * PAD + q * 8];
      bk[jn][1] = *(const short8*)&Ks[(jn * 16 + r) * PAD + 32 + q * 8];
    }

    // S = Q K^T (pre-scaled); exp2; accumulate lsum; pack P to LDS (pi order)
#pragma unroll
    for (int i = 0; i < 2; ++i) {
      float4v sacc[4];
      __builtin_amdgcn_s_setprio(1);
#pragma unroll
      for (int jn = 0; jn < 4; ++jn) {
        float4v z = {0.f, 0.f, 0.f, 0.f};
        z = MFMA(aq[i][0], bk[jn][0], z);
        z = MFMA(aq[i][1], bk[jn][1], z);
        sacc[jn] = z;
      }
      __builtin_amdgcn_s_setprio(0);
#pragma unroll
      for (int rg = 0; rg < 4; ++rg) {
        float p0 = fast_exp2(sacc[0][rg]);
        float p1 = fast_exp2(sacc[1][rg]);
        float p2 = fast_exp2(sacc[2][rg]);
        float p3 = fast_exp2(sacc[3][rg]);
        lsum[i * 4 + rg] += (p0 + p1) + (p2 + p3);
        // truncating bf16 pack: halfwords [pi=4r+0..3] = (p0,p1,p2,p3)
        uint2 pk;
        pk.x = __builtin_amdgcn_perm(fu(p1), fu(p0), 0x07060302u);
        pk.y = __builtin_amdgcn_perm(fu(p3), fu(p2), 0x07060302u);
        *(uint2*)&Ps[(w * 32 + i * 16 + q * 4 + rg) * PAD + r * 4] = pk;
      }
    }

    // V fragments: direct b128 reads (Vst already pi-ordered)
    short8 bv[4][2];
#pragma unroll
    for (int jv = 0; jv < 4; ++jv) {
      bv[jv][0] = *(const short8*)&Vst[(jv * 16 + r) * PAD + q * 8];
      bv[jv][1] = *(const short8*)&Vst[(jv * 16 + r) * PAD + 32 + q * 8];
    }

    // O += P V  (P A-frags are direct b128 reads in pi order)
#pragma unroll
    for (int i = 0; i < 2; ++i) {
      short8 ap0 = *(const short8*)&Ps[(w * 32 + i * 16 + r) * PAD + q * 8];
      short8 ap1 = *(const short8*)&Ps[(w * 32 + i * 16 + r) * PAD + 32 + q * 8];
      __builtin_amdgcn_s_setprio(1);
#pragma unroll
      for (int jv = 0; jv < 4; ++jv) {
        oacc[i][jv] = MFMA(ap0, bv[jv][0], oacc[i][jv]);
        oacc[i][jv] = MFMA(ap1, bv[jv][1], oacc[i][jv]);
      }
      __builtin_amdgcn_s_setprio(0);
    }

    // write next tile into LDS after all waves finished reading current one
    if (has_next) {
      __syncthreads();
      *(uint4*)lK0 = kr0; *(uint4*)lK1 = kr1;
      *(uint4*)lV0 = vr0; *(uint4*)lV1 = vr1;
      __syncthreads();
    }
  }

  // one-time row-sum reduction across the 16 r-lanes
#pragma unroll
  for (int t = 0; t < 8; ++t)
#pragma unroll
    for (int d = 1; d < 16; d <<= 1) lsum[t] += __shfl_xor(lsum[t], d);

#pragma unroll
  for (int i = 0; i < 2; ++i)
#pragma unroll
    for (int jv = 0; jv < 4; ++jv)
#pragma unroll
      for (int rg = 0; rg < 4; ++rg) {
        int row = b * 2048 + l0 + w * 32 + i * 16 + q * 4 + rg;
        int col = h * 64 + jv * 16 + r;
        O[(size_t)row * 1024 + col] = f2b(oacc[i][jv][rg] / lsum[i * 4 + rg]);
      }
}

// --- row LayerNorm: mean, std(ddof=1), /(sigma+1e-3)*a + b  (all fp32)
__global__ __launch_bounds__(256) void ln_kernel(const float* __restrict__ Z,
                                                 const float* __restrict__ ga,
                                                 const float* __restrict__ be,
                                                 float* __restrict__ out) {
  const int row = blockIdx.x;
  const float* z = Z + (size_t)row * 1024;
  const int tid = threadIdx.x;
  float v[4], s = 0.f, sq = 0.f;
#pragma unroll
  for (int i = 0; i < 4; ++i) {
    v[i] = z[tid + i * 256];
    s += v[i];
    sq += v[i] * v[i];
  }
#pragma unroll
  for (int d = 1; d < 64; d <<= 1) { s += __shfl_xor(s, d); sq += __shfl_xor(sq, d); }
  __shared__ float ss[4], ssq[4];
  const int w = tid >> 6, lane = tid & 63;
  if (lane == 0) { ss[w] = s; ssq[w] = sq; }
  __syncthreads();
  s = ss[0] + ss[1] + ss[2] + ss[3];
  sq = ssq[0] + ssq[1] + ssq[2] + ssq[3];
  float mu = s * (1.f / 1024.f);
  float var = fmaxf((sq - 1024.f * mu * mu) * (1.f / 1023.f), 0.f);
  float inv = 1.f / (sqrtf(var) + 1e-3f);
#pragma unroll
  for (int i = 0; i < 4; ++i) {
    int c = tid + i * 256;
    out[(size_t)row * 1024 + c] = (v[i] - mu) * inv * ga[c] + be[c];
  }
}

extern "C" void kernel_launch(void* const* d_in, const int* in_sizes, int n_in,
                              void* d_out, int out_size, void* d_ws, size_t ws_size,
                              hipStream_t stream) {
  (void)in_sizes; (void)n_in; (void)out_size; (void)ws_size;
  const float* q      = (const float*)d_in[0];
  const float* w_qs   = (const float*)d_in[1];
  const float* w_ks   = (const float*)d_in[2];
  const float* w_vs   = (const float*)d_in[3];
  const float* proj_w = (const float*)d_in[4];
  const float* proj_b = (const float*)d_in[5];
  const float* ln_a   = (const float*)d_in[6];
  const float* ln_b   = (const float*)d_in[7];
  float* out = (float*)d_out;

  // ws (88 MB): [Qb 16MB][O 16MB][QK 32MB][Wt 6MB][Pb 2MB][Vt 16MB]
  // Z (fp32, 32MB) aliases QK (dead after attention).
  unsigned short* Qb  = (unsigned short*)d_ws;
  unsigned short* O   = Qb + (size_t)Mrows * Dm;
  unsigned short* QK  = O + (size_t)Mrows * Dm;
  unsigned short* Wt  = QK + (size_t)Mrows * 2048;
  unsigned short* Pb  = Wt + (size_t)NQKV * Dm;
  unsigned short* Vt  = Pb + (size_t)NP_ELEMS;
  float* Z = (float*)QK;

  prep_kernel<<<dim3(NCONV + 768), dim3(256), 0, stream>>>(
      q, proj_w, w_qs, w_ks, w_vs, Qb, Pb, Wt);
  gemm_bt<0><<<dim3(NQKV / 128, Mrows / 128), dim3(256), 0, stream>>>(
      Qb, Wt, QK, Vt, nullptr, nullptr, nullptr, NQKV, Dm);
  attn_kernel<<<dim3(16 * NH * Bb), dim3(256), 0, stream>>>(QK, Vt, O);
  gemm_bt<1><<<dim3(Dm / 128, Mrows / 128), dim3(256), 0, stream>>>(
      O, Pb, nullptr, nullptr, Z, proj_b, q, Dm, Dm);
  ln_kernel<<<dim3(Mrows), dim3(256), 0, stream>>>(Z, ln_a, ln_b, out);
}

// Round 7
// 295.302 us; speedup vs baseline: 2.0196x; 1.0531x over previous
//
#include <hip/hip_runtime.h>
#include <hip/hip_bf16.h>
#include <cstdint>

// ---------------------------------------------------------------------------
// MultiHeadAttention (B=4, L=2048, d_model=1024, 16 heads, d_k=d_v=64)
// Inputs/outputs fp32. Internals: bf16 MFMA, fp32 accum.
// R2-R5: V pre-transposed; no-max softmax (exp2, pre-scaled Q); pi-ordered Vt;
//     attn T14 async-STAGE + T5 setprio.
// R6-R8 (FAILED, reverted): attn K-direct-from-global.
// R9: T1 XCD swizzles (attn FETCH 139->24.6MB).
// R10: GEMM BK=64 + source-swizzled staging; prep fusion. 335->311us.
// R11: attn 8-wave blocks (512thr, 256 q-rows) -> K/V staged once per 256
//     rows (half the staging + half the K/V fetch; same 16 waves/CU);
//     lsum via all-ones-MFMA column (kills 24 VALU adds/tile + end shuffles;
//     denominator now numerically matches bf16-P numerator);
//     conv/ln float4 vectorization (G13).
// ---------------------------------------------------------------------------

typedef __attribute__((ext_vector_type(8))) short   short8;
typedef __attribute__((ext_vector_type(8))) __bf16  bf16x8;
typedef __attribute__((ext_vector_type(4))) float   float4v;

template <typename V>
__device__ __forceinline__ auto mfma_sel(V a, V b, float4v c, int)
    -> decltype(__builtin_amdgcn_mfma_f32_16x16x32_bf16(a, b, c, 0, 0, 0)) {
  return __builtin_amdgcn_mfma_f32_16x16x32_bf16(a, b, c, 0, 0, 0);
}
template <typename V>
__device__ __forceinline__ float4v mfma_sel(V a, V b, float4v c, long) {
  return __builtin_amdgcn_mfma_f32_16x16x32_bf16(
      __builtin_bit_cast(bf16x8, a), __builtin_bit_cast(bf16x8, b), c, 0, 0, 0);
}
__device__ __forceinline__ float4v MFMA(short8 a, short8 b, float4v c) {
  return mfma_sel(a, b, c, 0);
}

__device__ __forceinline__ unsigned short f2b(float f) {
  union { float f; unsigned int u; } x; x.f = f;
  unsigned int r = x.u + 0x7FFFu + ((x.u >> 16) & 1u);  // RNE
  return (unsigned short)(r >> 16);
}
__device__ __forceinline__ unsigned int fu(float f) {
  union { float f; unsigned int u; } x; x.f = f; return x.u;
}
__device__ __forceinline__ float fast_exp2(float x) {
#if __has_builtin(__builtin_amdgcn_exp2f)
  return __builtin_amdgcn_exp2f(x);
#else
  return exp2f(x);
#endif
}

// async global->LDS, 16B per lane; LDS dest = wave-uniform base + lane*16
__device__ __forceinline__ void async_cp16(const unsigned short* g, unsigned short* l) {
  __builtin_amdgcn_global_load_lds(
      (const __attribute__((address_space(1))) void*)g,
      (__attribute__((address_space(3))) void*)l, 16, 0, 0);
}

constexpr int Bb = 4, Ls = 2048, Dm = 1024, NH = 16;
constexpr int Mrows = Bb * Ls;          // 8192
constexpr int NQKV = 3 * Dm;            // 3072
constexpr int NQ_ELEMS = Mrows * Dm;    // 8388608
constexpr int NP_ELEMS = Dm * Dm;       // 1048576
constexpr int PAD = 72;                 // attn LDS row stride (halfwords)
constexpr int NCONV4 = (NQ_ELEMS + NP_ELEMS) / 1024;  // 9216 conv blocks (x4 vec)

// --- fused prep: fp32->bf16 conv of q (8M) + proj_w (1M) [float4-vectorized],
// and LDS-transpose repack of w_qs/w_ks/w_vs [16][1024][64] -> Wt[3072][1024].
__global__ __launch_bounds__(256) void prep_kernel(const float* __restrict__ q,
                                                   const float* __restrict__ pw,
                                                   const float* __restrict__ wq,
                                                   const float* __restrict__ wk,
                                                   const float* __restrict__ wv,
                                                   unsigned short* __restrict__ Qb,
                                                   unsigned short* __restrict__ Pb,
                                                   unsigned short* __restrict__ Wt) {
  const int bid = blockIdx.x;
  if (bid < NCONV4) {
    int idx = (bid * 256 + threadIdx.x) * 4;
    const float* src;
    unsigned short* dst;
    if (idx < NQ_ELEMS) { src = q + idx; dst = Qb + idx; }
    else { src = pw + (idx - NQ_ELEMS); dst = Pb + (idx - NQ_ELEMS); }
    float4 f = *(const float4*)src;
    unsigned short o[4] = {f2b(f.x), f2b(f.y), f2b(f.z), f2b(f.w)};
    *(uint2*)dst = *(const uint2*)o;
    return;
  }
  // repack path: 768 blocks
  const int rb = bid - NCONV4;
  const int which = rb >> 8;           // 0,1,2
  const int h = (rb >> 4) & 15, dt = rb & 15;
  const float* w = (which == 0) ? wq : (which == 1 ? wk : wv);

  __shared__ float tile[64][65];
  const int kk = threadIdx.x & 63, dd = threadIdx.x >> 6;  // 4 rows/pass
#pragma unroll
  for (int p = 0; p < 16; ++p) {
    int d = dt * 64 + p * 4 + dd;
    tile[p * 4 + dd][kk] = w[(size_t)(h * 1024 + d) * 64 + kk];
  }
  __syncthreads();
  const int kkw = threadIdx.x >> 2, c0 = (threadIdx.x & 3) * 16;
  unsigned short tmp[16];
#pragma unroll
  for (int j = 0; j < 16; ++j) tmp[j] = f2b(tile[c0 + j][kkw]);
  unsigned short* dst =
      Wt + (size_t)(which * 1024 + h * 64 + kkw) * 1024 + dt * 64 + c0;
  *(uint4*)&dst[0] = *(const uint4*)&tmp[0];
  *(uint4*)&dst[8] = *(const uint4*)&tmp[8];
}

// --- C = A[M][K] * Bt[N][K]^T (bf16), 128x128 tile, BK=64, 4 waves 64x64,
// async global_load_lds width-16 staging, T1 XCD swizzle (R10 structure).
template <int MODE>
__global__ __launch_bounds__(256) void gemm_bt(const unsigned short* __restrict__ A,
                                               const unsigned short* __restrict__ Bt,
                                               unsigned short* __restrict__ QK,
                                               unsigned short* __restrict__ Vt,
                                               float* __restrict__ Cf,
                                               const float* __restrict__ bias,
                                               const float* __restrict__ resid,
                                               int N, int K) {
  __shared__ __align__(16) unsigned short As[128 * 64];
  __shared__ __align__(16) unsigned short Bs[128 * 64];
  const int tid = threadIdx.x;
  const int lane = tid & 63, w = tid >> 6;
  const int wm = (w >> 1) * 64, wn = (w & 1) * 64;

  // T1: raw wg -> XCD-contiguous logical tile (nwg % 8 == 0 for both modes)
  const int Nx = gridDim.x;
  const int cpx = (Nx * gridDim.y) >> 3;
  const int wg = blockIdx.y * Nx + blockIdx.x;
  const int lg = (wg & 7) * cpx + (wg >> 3);
  const int m0 = (lg / Nx) * 128, n0 = (lg % Nx) * 128;
  const int r = lane & 15, q = lane >> 4;

  // staging maps: call c stages rows 32c..32c+31; thread covers row
  // 8w + (lane>>3); global col8 pre-swizzled by row&7 = (lane>>3)&7.
  const int srow = 8 * w + (lane >> 3);
  const int scol = ((lane & 7) ^ ((lane >> 3) & 7)) * 8;
  const unsigned short* gA = A + (size_t)(m0 + srow) * K + scol;
  const unsigned short* gB = Bt + (size_t)(n0 + srow) * K + scol;
  unsigned short* lA = As + w * 512;  // wave-uniform base (hw units)
  unsigned short* lB = Bs + w * 512;

  float4v acc[4][4] = {};

  for (int k0 = 0; k0 < K; k0 += 64) {
#pragma unroll
    for (int c = 0; c < 4; ++c) {
      async_cp16(gA + (size_t)(32 * c) * K + k0, lA + c * 2048);
      async_cp16(gB + (size_t)(32 * c) * K + k0, lB + c * 2048);
    }
    __syncthreads();
#pragma unroll
    for (int ks = 0; ks < 2; ++ks) {
      short8 af[4], bfr[4];
#pragma unroll
      for (int i = 0; i < 4; ++i)
        af[i] = *(const short8*)&As[(wm + i * 16 + r) * 64 +
                                    (((ks << 2) + q) ^ (r & 7)) * 8];
#pragma unroll
      for (int j = 0; j < 4; ++j)
        bfr[j] = *(const short8*)&Bs[(wn + j * 16 + r) * 64 +
                                     (((ks << 2) + q) ^ (r & 7)) * 8];
#pragma unroll
      for (int i = 0; i < 4; ++i)
#pragma unroll
        for (int j = 0; j < 4; ++j)
          acc[i][j] = MFMA(af[i], bfr[j], acc[i][j]);
    }
    __syncthreads();
  }

  if (MODE == 0 && n0 >= 2048) {
    // pi-ordered V: lane writes positions [16q, 16q+16) of token-tile m0+wm
#pragma unroll
    for (int j = 0; j < 4; ++j) {
      int dv = n0 + wn + j * 16 + r - 2048;
      unsigned short t16[16];
#pragma unroll
      for (int i = 0; i < 4; ++i)
#pragma unroll
        for (int rg = 0; rg < 4; ++rg)
          t16[4 * rg + i] = f2b(acc[i][j][rg]);
      unsigned short* dst = Vt + (size_t)dv * 8192 + (m0 + wm) + 16 * q;
      *(uint4*)&dst[0] = *(const uint4*)&t16[0];
      *(uint4*)&dst[8] = *(const uint4*)&t16[8];
    }
  } else {
    const float qscale = (MODE == 0 && n0 < 1024) ? 0.045084230f /*log2e/32*/ : 1.0f;
#pragma unroll
    for (int i = 0; i < 4; ++i)
#pragma unroll
      for (int j = 0; j < 4; ++j)
#pragma unroll
        for (int rg = 0; rg < 4; ++rg) {
          int row = m0 + wm + i * 16 + q * 4 + rg;
          int col = n0 + wn + j * 16 + r;
          float v = acc[i][j][rg];
          if (MODE == 0) {
            QK[(size_t)row * 2048 + col] = f2b(v * qscale);
          } else {
            v += bias[col] + resid[(size_t)row * N + col];
            Cf[(size_t)row * N + col] = v;
          }
        }
  }
}

// --- flash attention (no-max softmax): one block = (h, b, 256 q-rows),
// 8 waves x 32 rows (R11). QK[8192][2048]: cols [0,1024)=Q (pre-scaled),
// [1024,2048)=K. Vt[1024][8192] pi-ordered per 64-token tile.
// K/V tile staged ONCE per 256 q-rows (half the R10 staging + fetch).
// lsum computed by all-ones-MFMA column: every lane's oext[i][rg] = row-sum.
__global__ __launch_bounds__(512) void attn_kernel(const unsigned short* __restrict__ QK,
                                                   const unsigned short* __restrict__ Vt,
                                                   unsigned short* __restrict__ O) {
  const int bx = blockIdx.x;
  // T1: 512 blocks; logical = (bx%8)*64 + bx/8; hb = lg/8, qt = lg%8
  const int lg = (bx & 7) * 64 + (bx >> 3);
  const int qt = lg & 7, hb = lg >> 3;
  const int h = hb & 15, b = hb >> 4;
  const int tid = threadIdx.x, lane = tid & 63, w = tid >> 6;
  const int r = lane & 15, q = lane >> 4;

  __shared__ __align__(16) unsigned short Ks[64 * PAD];    // [key][d]
  __shared__ __align__(16) unsigned short Vst[64 * PAD];   // [dv][pi(key)]
  __shared__ __align__(16) unsigned short Ps[256 * PAD];   // [qrow][pi(key)]

  const size_t RS = 2048;
  const int l0 = qt * 256;

  short8 aq[2][2];
#pragma unroll
  for (int i = 0; i < 2; ++i) {
    const unsigned short* Qr =
        QK + (size_t)(b * 2048 + l0 + w * 32 + i * 16 + r) * RS + h * 64;
    aq[i][0] = *(const short8*)&Qr[q * 8];
    aq[i][1] = *(const short8*)&Qr[32 + q * 8];
  }

  // staging maps: 512 threads cover the full 64x64 tile in one pass:
  // row = tid>>3 (0..63), off = (tid&7)*8
  const int row0 = tid >> 3, off0 = (tid & 7) * 8;
  const unsigned short* gK0 = QK + (size_t)(b * 2048 + row0) * RS + 1024 + h * 64 + off0;
  const unsigned short* gV0 = Vt + (size_t)(h * 64 + row0) * 8192 + b * 2048 + off0;
  unsigned short* lK0 = &Ks[row0 * PAD + off0];
  unsigned short* lV0 = &Vst[row0 * PAD + off0];

  // prologue: stage tile kt=0
  uint4 kr0 = *(const uint4*)gK0;
  uint4 vr0 = *(const uint4*)gV0;
  *(uint4*)lK0 = kr0;
  *(uint4*)lV0 = vr0;
  __syncthreads();

  float4v oacc[2][4] = {};
  float4v oext[2] = {};
  const short8 vones = {16256, 16256, 16256, 16256,
                        16256, 16256, 16256, 16256};  // bf16 1.0 x8

  for (int kt = 0; kt < 2048; kt += 64) {
    const bool has_next = (kt + 64) < 2048;
    // T14: issue next tile's global loads now; they land during compute
    if (has_next) {
      kr0 = *(const uint4*)(gK0 + (size_t)(kt + 64) * RS);
      vr0 = *(const uint4*)(gV0 + (kt + 64));
    }

    // K fragments (shared across both i row-blocks)
    short8 bk[4][2];
#pragma unroll
    for (int jn = 0; jn < 4; ++jn) {
      bk[jn][0] = *(const short8*)&Ks[(jn * 16 + r) * PAD + q * 8];
      bk[jn][1] = *(const short8*)&Ks[(jn * 16 + r) * PAD + 32 + q * 8];
    }

    // S = Q K^T (pre-scaled); exp2; pack P to LDS (pi order)
#pragma unroll
    for (int i = 0; i < 2; ++i) {
      float4v sacc[4];
      __builtin_amdgcn_s_setprio(1);
#pragma unroll
      for (int jn = 0; jn < 4; ++jn) {
        float4v z = {0.f, 0.f, 0.f, 0.f};
        z = MFMA(aq[i][0], bk[jn][0], z);
        z = MFMA(aq[i][1], bk[jn][1], z);
        sacc[jn] = z;
      }
      __builtin_amdgcn_s_setprio(0);
#pragma unroll
      for (int rg = 0; rg < 4; ++rg) {
        float p0 = fast_exp2(sacc[0][rg]);
        float p1 = fast_exp2(sacc[1][rg]);
        float p2 = fast_exp2(sacc[2][rg]);
        float p3 = fast_exp2(sacc[3][rg]);
        // truncating bf16 pack: halfwords [pi=4r+0..3] = (p0,p1,p2,p3)
        uint2 pk;
        pk.x = __builtin_amdgcn_perm(fu(p1), fu(p0), 0x07060302u);
        pk.y = __builtin_amdgcn_perm(fu(p3), fu(p2), 0x07060302u);
        *(uint2*)&Ps[(w * 32 + i * 16 + q * 4 + rg) * PAD + r * 4] = pk;
      }
    }

    // V fragments: direct b128 reads (Vst already pi-ordered)
    short8 bv[4][2];
#pragma unroll
    for (int jv = 0; jv < 4; ++jv) {
      bv[jv][0] = *(const short8*)&Vst[(jv * 16 + r) * PAD + q * 8];
      bv[jv][1] = *(const short8*)&Vst[(jv * 16 + r) * PAD + 32 + q * 8];
    }

    // O += P V ; row-sum += P * ones  (P A-frags direct b128 in pi order)
#pragma unroll
    for (int i = 0; i < 2; ++i) {
      short8 ap0 = *(const short8*)&Ps[(w * 32 + i * 16 + r) * PAD + q * 8];
      short8 ap1 = *(const short8*)&Ps[(w * 32 + i * 16 + r) * PAD + 32 + q * 8];
      __builtin_amdgcn_s_setprio(1);
#pragma unroll
      for (int jv = 0; jv < 4; ++jv) {
        oacc[i][jv] = MFMA(ap0, bv[jv][0], oacc[i][jv]);
        oacc[i][jv] = MFMA(ap1, bv[jv][1], oacc[i][jv]);
      }
      oext[i] = MFMA(ap0, vones, oext[i]);
      oext[i] = MFMA(ap1, vones, oext[i]);
      __builtin_amdgcn_s_setprio(0);
    }

    // write next tile into LDS after all waves finished reading current one
    if (has_next) {
      __syncthreads();
      *(uint4*)lK0 = kr0;
      *(uint4*)lV0 = vr0;
      __syncthreads();
    }
  }

#pragma unroll
  for (int i = 0; i < 2; ++i)
#pragma unroll
    for (int jv = 0; jv < 4; ++jv)
#pragma unroll
      for (int rg = 0; rg < 4; ++rg) {
        int row = b * 2048 + l0 + w * 32 + i * 16 + q * 4 + rg;
        int col = h * 64 + jv * 16 + r;
        O[(size_t)row * 1024 + col] = f2b(oacc[i][jv][rg] / oext[i][rg]);
      }
}

// --- row LayerNorm: mean, std(ddof=1), /(sigma+1e-3)*a + b  (all fp32)
// R11: float4-vectorized loads/stores.
__global__ __launch_bounds__(256) void ln_kernel(const float* __restrict__ Z,
                                                 const float* __restrict__ ga,
                                                 const float* __restrict__ be,
                                                 float* __restrict__ out) {
  const int row = blockIdx.x;
  const float* z = Z + (size_t)row * 1024;
  const int tid = threadIdx.x;
  float4 v = ((const float4*)z)[tid];
  float s = (v.x + v.y) + (v.z + v.w);
  float sq = (v.x * v.x + v.y * v.y) + (v.z * v.z + v.w * v.w);
#pragma unroll
  for (int d = 1; d < 64; d <<= 1) { s += __shfl_xor(s, d); sq += __shfl_xor(sq, d); }
  __shared__ float ss[4], ssq[4];
  const int w = tid >> 6, lane = tid & 63;
  if (lane == 0) { ss[w] = s; ssq[w] = sq; }
  __syncthreads();
  s = ss[0] + ss[1] + ss[2] + ss[3];
  sq = ssq[0] + ssq[1] + ssq[2] + ssq[3];
  float mu = s * (1.f / 1024.f);
  float var = fmaxf((sq - 1024.f * mu * mu) * (1.f / 1023.f), 0.f);
  float inv = 1.f / (sqrtf(var) + 1e-3f);
  float4 g = ((const float4*)ga)[tid];
  float4 bb = ((const float4*)be)[tid];
  float4 o;
  o.x = (v.x - mu) * inv * g.x + bb.x;
  o.y = (v.y - mu) * inv * g.y + bb.y;
  o.z = (v.z - mu) * inv * g.z + bb.z;
  o.w = (v.w - mu) * inv * g.w + bb.w;
  ((float4*)(out + (size_t)row * 1024))[tid] = o;
}

extern "C" void kernel_launch(void* const* d_in, const int* in_sizes, int n_in,
                              void* d_out, int out_size, void* d_ws, size_t ws_size,
                              hipStream_t stream) {
  (void)in_sizes; (void)n_in; (void)out_size; (void)ws_size;
  const float* q      = (const float*)d_in[0];
  const float* w_qs   = (const float*)d_in[1];
  const float* w_ks   = (const float*)d_in[2];
  const float* w_vs   = (const float*)d_in[3];
  const float* proj_w = (const float*)d_in[4];
  const float* proj_b = (const float*)d_in[5];
  const float* ln_a   = (const float*)d_in[6];
  const float* ln_b   = (const float*)d_in[7];
  float* out = (float*)d_out;

  // ws (88 MB): [Qb 16MB][O 16MB][QK 32MB][Wt 6MB][Pb 2MB][Vt 16MB]
  // Z (fp32, 32MB) aliases QK (dead after attention).
  unsigned short* Qb  = (unsigned short*)d_ws;
  unsigned short* O   = Qb + (size_t)Mrows * Dm;
  unsigned short* QK  = O + (size_t)Mrows * Dm;
  unsigned short* Wt  = QK + (size_t)Mrows * 2048;
  unsigned short* Pb  = Wt + (size_t)NQKV * Dm;
  unsigned short* Vt  = Pb + (size_t)NP_ELEMS;
  float* Z = (float*)QK;

  prep_kernel<<<dim3(NCONV4 + 768), dim3(256), 0, stream>>>(
      q, proj_w, w_qs, w_ks, w_vs, Qb, Pb, Wt);
  gemm_bt<0><<<dim3(NQKV / 128, Mrows / 128), dim3(256), 0, stream>>>(
      Qb, Wt, QK, Vt, nullptr, nullptr, nullptr, NQKV, Dm);
  attn_kernel<<<dim3(8 * NH * Bb), dim3(512), 0, stream>>>(QK, Vt, O);
  gemm_bt<1><<<dim3(Dm / 128, Mrows / 128), dim3(256), 0, stream>>>(
      O, Pb, nullptr, nullptr, Z, proj_b, q, Dm, Dm);
  ln_kernel<<<dim3(Mrows), dim3(256), 0, stream>>>(Z, ln_a, ln_b, out);
}

// Round 8
// 281.072 us; speedup vs baseline: 2.1218x; 1.0506x over previous
//
#include <hip/hip_runtime.h>
#include <hip/hip_bf16.h>
#include <cstdint>

// ---------------------------------------------------------------------------
// MultiHeadAttention (B=4, L=2048, d_model=1024, 16 heads, d_k=d_v=64)
// Inputs/outputs fp32. Internals: bf16 MFMA, fp32 accum.
// R2-R5: V pre-transposed; no-max softmax (exp2, pre-scaled Q); pi-ordered Vt;
//     attn T14 async-STAGE + T5 setprio.
// R6-R8 (FAILED, reverted): attn K-direct-from-global.
// R9: T1 XCD swizzles (attn FETCH 139->24.6MB).
// R10: GEMM BK=64 + source-swizzled staging; prep fusion. 335->311us.
// R11: attn 8-wave/256-row blocks; lsum via all-ones-MFMA; vec conv/ln.
//     311->295us (attn 102.4, MfmaUtil 31).
// R12: attn single-barrier K/V double-buffer — tile t reads buf[t&1] while
//     prefetched tile t+1 is written to buf[~t&1]; ONE barrier per tile
//     (was two, with staging serialized between them). Ps stays single
//     (per-wave rows only). LDS 55.3->73.7KB, still 2 blocks/CU.
// ---------------------------------------------------------------------------

typedef __attribute__((ext_vector_type(8))) short   short8;
typedef __attribute__((ext_vector_type(8))) __bf16  bf16x8;
typedef __attribute__((ext_vector_type(4))) float   float4v;

template <typename V>
__device__ __forceinline__ auto mfma_sel(V a, V b, float4v c, int)
    -> decltype(__builtin_amdgcn_mfma_f32_16x16x32_bf16(a, b, c, 0, 0, 0)) {
  return __builtin_amdgcn_mfma_f32_16x16x32_bf16(a, b, c, 0, 0, 0);
}
template <typename V>
__device__ __forceinline__ float4v mfma_sel(V a, V b, float4v c, long) {
  return __builtin_amdgcn_mfma_f32_16x16x32_bf16(
      __builtin_bit_cast(bf16x8, a), __builtin_bit_cast(bf16x8, b), c, 0, 0, 0);
}
__device__ __forceinline__ float4v MFMA(short8 a, short8 b, float4v c) {
  return mfma_sel(a, b, c, 0);
}

__device__ __forceinline__ unsigned short f2b(float f) {
  union { float f; unsigned int u; } x; x.f = f;
  unsigned int r = x.u + 0x7FFFu + ((x.u >> 16) & 1u);  // RNE
  return (unsigned short)(r >> 16);
}
__device__ __forceinline__ unsigned int fu(float f) {
  union { float f; unsigned int u; } x; x.f = f; return x.u;
}
__device__ __forceinline__ float fast_exp2(float x) {
#if __has_builtin(__builtin_amdgcn_exp2f)
  return __builtin_amdgcn_exp2f(x);
#else
  return exp2f(x);
#endif
}

// async global->LDS, 16B per lane; LDS dest = wave-uniform base + lane*16
__device__ __forceinline__ void async_cp16(const unsigned short* g, unsigned short* l) {
  __builtin_amdgcn_global_load_lds(
      (const __attribute__((address_space(1))) void*)g,
      (__attribute__((address_space(3))) void*)l, 16, 0, 0);
}

constexpr int Bb = 4, Ls = 2048, Dm = 1024, NH = 16;
constexpr int Mrows = Bb * Ls;          // 8192
constexpr int NQKV = 3 * Dm;            // 3072
constexpr int NQ_ELEMS = Mrows * Dm;    // 8388608
constexpr int NP_ELEMS = Dm * Dm;       // 1048576
constexpr int PAD = 72;                 // attn LDS row stride (halfwords)
constexpr int KVTILE = 64 * PAD;        // one K or V tile in halfwords
constexpr int NCONV4 = (NQ_ELEMS + NP_ELEMS) / 1024;  // 9216 conv blocks (x4 vec)

// --- fused prep: fp32->bf16 conv of q (8M) + proj_w (1M) [float4-vectorized],
// and LDS-transpose repack of w_qs/w_ks/w_vs [16][1024][64] -> Wt[3072][1024].
__global__ __launch_bounds__(256) void prep_kernel(const float* __restrict__ q,
                                                   const float* __restrict__ pw,
                                                   const float* __restrict__ wq,
                                                   const float* __restrict__ wk,
                                                   const float* __restrict__ wv,
                                                   unsigned short* __restrict__ Qb,
                                                   unsigned short* __restrict__ Pb,
                                                   unsigned short* __restrict__ Wt) {
  const int bid = blockIdx.x;
  if (bid < NCONV4) {
    int idx = (bid * 256 + threadIdx.x) * 4;
    const float* src;
    unsigned short* dst;
    if (idx < NQ_ELEMS) { src = q + idx; dst = Qb + idx; }
    else { src = pw + (idx - NQ_ELEMS); dst = Pb + (idx - NQ_ELEMS); }
    float4 f = *(const float4*)src;
    unsigned short o[4] = {f2b(f.x), f2b(f.y), f2b(f.z), f2b(f.w)};
    *(uint2*)dst = *(const uint2*)o;
    return;
  }
  // repack path: 768 blocks
  const int rb = bid - NCONV4;
  const int which = rb >> 8;           // 0,1,2
  const int h = (rb >> 4) & 15, dt = rb & 15;
  const float* w = (which == 0) ? wq : (which == 1 ? wk : wv);

  __shared__ float tile[64][65];
  const int kk = threadIdx.x & 63, dd = threadIdx.x >> 6;  // 4 rows/pass
#pragma unroll
  for (int p = 0; p < 16; ++p) {
    int d = dt * 64 + p * 4 + dd;
    tile[p * 4 + dd][kk] = w[(size_t)(h * 1024 + d) * 64 + kk];
  }
  __syncthreads();
  const int kkw = threadIdx.x >> 2, c0 = (threadIdx.x & 3) * 16;
  unsigned short tmp[16];
#pragma unroll
  for (int j = 0; j < 16; ++j) tmp[j] = f2b(tile[c0 + j][kkw]);
  unsigned short* dst =
      Wt + (size_t)(which * 1024 + h * 64 + kkw) * 1024 + dt * 64 + c0;
  *(uint4*)&dst[0] = *(const uint4*)&tmp[0];
  *(uint4*)&dst[8] = *(const uint4*)&tmp[8];
}

// --- C = A[M][K] * Bt[N][K]^T (bf16), 128x128 tile, BK=64, 4 waves 64x64,
// async global_load_lds width-16 staging, T1 XCD swizzle (R10 structure).
template <int MODE>
__global__ __launch_bounds__(256) void gemm_bt(const unsigned short* __restrict__ A,
                                               const unsigned short* __restrict__ Bt,
                                               unsigned short* __restrict__ QK,
                                               unsigned short* __restrict__ Vt,
                                               float* __restrict__ Cf,
                                               const float* __restrict__ bias,
                                               const float* __restrict__ resid,
                                               int N, int K) {
  __shared__ __align__(16) unsigned short As[128 * 64];
  __shared__ __align__(16) unsigned short Bs[128 * 64];
  const int tid = threadIdx.x;
  const int lane = tid & 63, w = tid >> 6;
  const int wm = (w >> 1) * 64, wn = (w & 1) * 64;

  // T1: raw wg -> XCD-contiguous logical tile (nwg % 8 == 0 for both modes)
  const int Nx = gridDim.x;
  const int cpx = (Nx * gridDim.y) >> 3;
  const int wg = blockIdx.y * Nx + blockIdx.x;
  const int lg = (wg & 7) * cpx + (wg >> 3);
  const int m0 = (lg / Nx) * 128, n0 = (lg % Nx) * 128;
  const int r = lane & 15, q = lane >> 4;

  // staging maps: call c stages rows 32c..32c+31; thread covers row
  // 8w + (lane>>3); global col8 pre-swizzled by row&7 = (lane>>3)&7.
  const int srow = 8 * w + (lane >> 3);
  const int scol = ((lane & 7) ^ ((lane >> 3) & 7)) * 8;
  const unsigned short* gA = A + (size_t)(m0 + srow) * K + scol;
  const unsigned short* gB = Bt + (size_t)(n0 + srow) * K + scol;
  unsigned short* lA = As + w * 512;  // wave-uniform base (hw units)
  unsigned short* lB = Bs + w * 512;

  float4v acc[4][4] = {};

  for (int k0 = 0; k0 < K; k0 += 64) {
#pragma unroll
    for (int c = 0; c < 4; ++c) {
      async_cp16(gA + (size_t)(32 * c) * K + k0, lA + c * 2048);
      async_cp16(gB + (size_t)(32 * c) * K + k0, lB + c * 2048);
    }
    __syncthreads();
#pragma unroll
    for (int ks = 0; ks < 2; ++ks) {
      short8 af[4], bfr[4];
#pragma unroll
      for (int i = 0; i < 4; ++i)
        af[i] = *(const short8*)&As[(wm + i * 16 + r) * 64 +
                                    (((ks << 2) + q) ^ (r & 7)) * 8];
#pragma unroll
      for (int j = 0; j < 4; ++j)
        bfr[j] = *(const short8*)&Bs[(wn + j * 16 + r) * 64 +
                                     (((ks << 2) + q) ^ (r & 7)) * 8];
#pragma unroll
      for (int i = 0; i < 4; ++i)
#pragma unroll
        for (int j = 0; j < 4; ++j)
          acc[i][j] = MFMA(af[i], bfr[j], acc[i][j]);
    }
    __syncthreads();
  }

  if (MODE == 0 && n0 >= 2048) {
    // pi-ordered V: lane writes positions [16q, 16q+16) of token-tile m0+wm
#pragma unroll
    for (int j = 0; j < 4; ++j) {
      int dv = n0 + wn + j * 16 + r - 2048;
      unsigned short t16[16];
#pragma unroll
      for (int i = 0; i < 4; ++i)
#pragma unroll
        for (int rg = 0; rg < 4; ++rg)
          t16[4 * rg + i] = f2b(acc[i][j][rg]);
      unsigned short* dst = Vt + (size_t)dv * 8192 + (m0 + wm) + 16 * q;
      *(uint4*)&dst[0] = *(const uint4*)&t16[0];
      *(uint4*)&dst[8] = *(const uint4*)&t16[8];
    }
  } else {
    const float qscale = (MODE == 0 && n0 < 1024) ? 0.045084230f /*log2e/32*/ : 1.0f;
#pragma unroll
    for (int i = 0; i < 4; ++i)
#pragma unroll
      for (int j = 0; j < 4; ++j)
#pragma unroll
        for (int rg = 0; rg < 4; ++rg) {
          int row = m0 + wm + i * 16 + q * 4 + rg;
          int col = n0 + wn + j * 16 + r;
          float v = acc[i][j][rg];
          if (MODE == 0) {
            QK[(size_t)row * 2048 + col] = f2b(v * qscale);
          } else {
            v += bias[col] + resid[(size_t)row * N + col];
            Cf[(size_t)row * N + col] = v;
          }
        }
  }
}

// --- flash attention (no-max softmax): one block = (h, b, 256 q-rows),
// 8 waves x 32 rows. QK[8192][2048]: cols [0,1024)=Q (pre-scaled),
// [1024,2048)=K. Vt[1024][8192] pi-ordered per 64-token tile.
// R12: K/V double-buffered in LDS, ONE barrier per tile (after staging
// writes). Reg-prefetch of t+1 at loop top (T14); Ps single-buffered
// (per-wave rows only). lsum via all-ones-MFMA column.
__global__ __launch_bounds__(512) void attn_kernel(const unsigned short* __restrict__ QK,
                                                   const unsigned short* __restrict__ Vt,
                                                   unsigned short* __restrict__ O) {
  const int bx = blockIdx.x;
  // T1: 512 blocks; logical = (bx%8)*64 + bx/8; hb = lg/8, qt = lg%8
  const int lg = (bx & 7) * 64 + (bx >> 3);
  const int qt = lg & 7, hb = lg >> 3;
  const int h = hb & 15, b = hb >> 4;
  const int tid = threadIdx.x, lane = tid & 63, w = tid >> 6;
  const int r = lane & 15, q = lane >> 4;

  __shared__ __align__(16) unsigned short Ks[2 * KVTILE];   // [buf][key][d]
  __shared__ __align__(16) unsigned short Vst[2 * KVTILE];  // [buf][dv][pi]
  __shared__ __align__(16) unsigned short Ps[256 * PAD];    // [qrow][pi(key)]

  const size_t RS = 2048;
  const int l0 = qt * 256;

  short8 aq[2][2];
#pragma unroll
  for (int i = 0; i < 2; ++i) {
    const unsigned short* Qr =
        QK + (size_t)(b * 2048 + l0 + w * 32 + i * 16 + r) * RS + h * 64;
    aq[i][0] = *(const short8*)&Qr[q * 8];
    aq[i][1] = *(const short8*)&Qr[32 + q * 8];
  }

  // staging maps: 512 threads cover the full 64x64 tile in one pass:
  // row = tid>>3 (0..63), off = (tid&7)*8
  const int row0 = tid >> 3, off0 = (tid & 7) * 8;
  const unsigned short* gK0 = QK + (size_t)(b * 2048 + row0) * RS + 1024 + h * 64 + off0;
  const unsigned short* gV0 = Vt + (size_t)(h * 64 + row0) * 8192 + b * 2048 + off0;
  unsigned short* lK = &Ks[row0 * PAD + off0];
  unsigned short* lV = &Vst[row0 * PAD + off0];

  // prologue: stage tile kt=0 into buf 0
  uint4 kr0 = *(const uint4*)gK0;
  uint4 vr0 = *(const uint4*)gV0;
  *(uint4*)lK = kr0;
  *(uint4*)lV = vr0;
  __syncthreads();

  float4v oacc[2][4] = {};
  float4v oext[2] = {};
  const short8 vones = {16256, 16256, 16256, 16256,
                        16256, 16256, 16256, 16256};  // bf16 1.0 x8
  int kb = 0;  // current K/V buffer offset (0 or KVTILE)

  for (int kt = 0; kt < 2048; kt += 64) {
    const bool has_next = (kt + 64) < 2048;
    // T14: issue next tile's global loads now; they land during compute
    if (has_next) {
      kr0 = *(const uint4*)(gK0 + (size_t)(kt + 64) * RS);
      vr0 = *(const uint4*)(gV0 + (kt + 64));
    }

    // K fragments (shared across both i row-blocks)
    short8 bk[4][2];
#pragma unroll
    for (int jn = 0; jn < 4; ++jn) {
      bk[jn][0] = *(const short8*)&Ks[kb + (jn * 16 + r) * PAD + q * 8];
      bk[jn][1] = *(const short8*)&Ks[kb + (jn * 16 + r) * PAD + 32 + q * 8];
    }

    // S = Q K^T (pre-scaled); exp2; pack P to LDS (pi order)
#pragma unroll
    for (int i = 0; i < 2; ++i) {
      float4v sacc[4];
      __builtin_amdgcn_s_setprio(1);
#pragma unroll
      for (int jn = 0; jn < 4; ++jn) {
        float4v z = {0.f, 0.f, 0.f, 0.f};
        z = MFMA(aq[i][0], bk[jn][0], z);
        z = MFMA(aq[i][1], bk[jn][1], z);
        sacc[jn] = z;
      }
      __builtin_amdgcn_s_setprio(0);
#pragma unroll
      for (int rg = 0; rg < 4; ++rg) {
        float p0 = fast_exp2(sacc[0][rg]);
        float p1 = fast_exp2(sacc[1][rg]);
        float p2 = fast_exp2(sacc[2][rg]);
        float p3 = fast_exp2(sacc[3][rg]);
        // truncating bf16 pack: halfwords [pi=4r+0..3] = (p0,p1,p2,p3)
        uint2 pk;
        pk.x = __builtin_amdgcn_perm(fu(p1), fu(p0), 0x07060302u);
        pk.y = __builtin_amdgcn_perm(fu(p3), fu(p2), 0x07060302u);
        *(uint2*)&Ps[(w * 32 + i * 16 + q * 4 + rg) * PAD + r * 4] = pk;
      }
    }

    // V fragments: direct b128 reads (Vst already pi-ordered)
    short8 bv[4][2];
#pragma unroll
    for (int jv = 0; jv < 4; ++jv) {
      bv[jv][0] = *(const short8*)&Vst[kb + (jv * 16 + r) * PAD + q * 8];
      bv[jv][1] = *(const short8*)&Vst[kb + (jv * 16 + r) * PAD + 32 + q * 8];
    }

    // O += P V ; row-sum += P * ones  (P A-frags direct b128 in pi order)
#pragma unroll
    for (int i = 0; i < 2; ++i) {
      short8 ap0 = *(const short8*)&Ps[(w * 32 + i * 16 + r) * PAD + q * 8];
      short8 ap1 = *(const short8*)&Ps[(w * 32 + i * 16 + r) * PAD + 32 + q * 8];
      __builtin_amdgcn_s_setprio(1);
#pragma unroll
      for (int jv = 0; jv < 4; ++jv) {
        oacc[i][jv] = MFMA(ap0, bv[jv][0], oacc[i][jv]);
        oacc[i][jv] = MFMA(ap1, bv[jv][1], oacc[i][jv]);
      }
      oext[i] = MFMA(ap0, vones, oext[i]);
      oext[i] = MFMA(ap1, vones, oext[i]);
      __builtin_amdgcn_s_setprio(0);
    }

    // write prefetched tile t+1 into the OTHER buffer; one barrier per tile.
    // (prev readers of that buffer finished before the barrier of tile t-1)
    if (has_next) {
      *(uint4*)(lK + (kb ^ KVTILE)) = kr0;
      *(uint4*)(lV + (kb ^ KVTILE)) = vr0;
      __syncthreads();
      kb ^= KVTILE;
    }
  }

#pragma unroll
  for (int i = 0; i < 2; ++i)
#pragma unroll
    for (int jv = 0; jv < 4; ++jv)
#pragma unroll
      for (int rg = 0; rg < 4; ++rg) {
        int row = b * 2048 + l0 + w * 32 + i * 16 + q * 4 + rg;
        int col = h * 64 + jv * 16 + r;
        O[(size_t)row * 1024 + col] = f2b(oacc[i][jv][rg] / oext[i][rg]);
      }
}

// --- row LayerNorm: mean, std(ddof=1), /(sigma+1e-3)*a + b  (all fp32)
// float4-vectorized loads/stores.
__global__ __launch_bounds__(256) void ln_kernel(const float* __restrict__ Z,
                                                 const float* __restrict__ ga,
                                                 const float* __restrict__ be,
                                                 float* __restrict__ out) {
  const int row = blockIdx.x;
  const float* z = Z + (size_t)row * 1024;
  const int tid = threadIdx.x;
  float4 v = ((const float4*)z)[tid];
  float s = (v.x + v.y) + (v.z + v.w);
  float sq = (v.x * v.x + v.y * v.y) + (v.z * v.z + v.w * v.w);
#pragma unroll
  for (int d = 1; d < 64; d <<= 1) { s += __shfl_xor(s, d); sq += __shfl_xor(sq, d); }
  __shared__ float ss[4], ssq[4];
  const int w = tid >> 6, lane = tid & 63;
  if (lane == 0) { ss[w] = s; ssq[w] = sq; }
  __syncthreads();
  s = ss[0] + ss[1] + ss[2] + ss[3];
  sq = ssq[0] + ssq[1] + ssq[2] + ssq[3];
  float mu = s * (1.f / 1024.f);
  float var = fmaxf((sq - 1024.f * mu * mu) * (1.f / 1023.f), 0.f);
  float inv = 1.f / (sqrtf(var) + 1e-3f);
  float4 g = ((const float4*)ga)[tid];
  float4 bb = ((const float4*)be)[tid];
  float4 o;
  o.x = (v.x - mu) * inv * g.x + bb.x;
  o.y = (v.y - mu) * inv * g.y + bb.y;
  o.z = (v.z - mu) * inv * g.z + bb.z;
  o.w = (v.w - mu) * inv * g.w + bb.w;
  ((float4*)(out + (size_t)row * 1024))[tid] = o;
}

extern "C" void kernel_launch(void* const* d_in, const int* in_sizes, int n_in,
                              void* d_out, int out_size, void* d_ws, size_t ws_size,
                              hipStream_t stream) {
  (void)in_sizes; (void)n_in; (void)out_size; (void)ws_size;
  const float* q      = (const float*)d_in[0];
  const float* w_qs   = (const float*)d_in[1];
  const float* w_ks   = (const float*)d_in[2];
  const float* w_vs   = (const float*)d_in[3];
  const float* proj_w = (const float*)d_in[4];
  const float* proj_b = (const float*)d_in[5];
  const float* ln_a   = (const float*)d_in[6];
  const float* ln_b   = (const float*)d_in[7];
  float* out = (float*)d_out;

  // ws (88 MB): [Qb 16MB][O 16MB][QK 32MB][Wt 6MB][Pb 2MB][Vt 16MB]
  // Z (fp32, 32MB) aliases QK (dead after attention).
  unsigned short* Qb  = (unsigned short*)d_ws;
  unsigned short* O   = Qb + (size_t)Mrows * Dm;
  unsigned short* QK  = O + (size_t)Mrows * Dm;
  unsigned short* Wt  = QK + (size_t)Mrows * 2048;
  unsigned short* Pb  = Wt + (size_t)NQKV * Dm;
  unsigned short* Vt  = Pb + (size_t)NP_ELEMS;
  float* Z = (float*)QK;

  prep_kernel<<<dim3(NCONV4 + 768), dim3(256), 0, stream>>>(
      q, proj_w, w_qs, w_ks, w_vs, Qb, Pb, Wt);
  gemm_bt<0><<<dim3(NQKV / 128, Mrows / 128), dim3(256), 0, stream>>>(
      Qb, Wt, QK, Vt, nullptr, nullptr, nullptr, NQKV, Dm);
  attn_kernel<<<dim3(8 * NH * Bb), dim3(512), 0, stream>>>(QK, Vt, O);
  gemm_bt<1><<<dim3(Dm / 128, Mrows / 128), dim3(256), 0, stream>>>(
      O, Pb, nullptr, nullptr, Z, proj_b, q, Dm, Dm);
  ln_kernel<<<dim3(Mrows), dim3(256), 0, stream>>>(Z, ln_a, ln_b, out);
}